// Round 19
// baseline (117.245 us; speedup 1.0000x reference)
//
#include <hip/hip_runtime.h>
#include <math.h>

#define N_PTS   16384
#define NT      1024         // 16-point tiles
#define NCHUNK  32
#define JT_CH   (NT/NCHUNK)  // 32 j-tiles per chunk
#define SUBT    8            // tiles per LDS staging round (16.9 KB -> 8 blocks/CU)
#define NSUB    (JT_CH/SUBT) // 4
#define NS      16           // gbuf slots per row
#define YSTRIDE 32           // pass-B y-blocks per chunk (grid-stride over slices)

typedef __attribute__((ext_vector_type(4))) float f32x4;
typedef __attribute__((ext_vector_type(8))) _Float16 half8;

union H8 { half8 h; float4 f; };

#define MED3(a,b,c) __builtin_amdgcn_fmed3f((a),(b),(c))

// branch-free exact top-4 (desc) insert: 1 max + 3 med3, ALL INDEPENDENT (1 dep level)
#define INS4(c, A0, A1, A2, A3) {        \
  float n0_ = fmaxf(A0, c);              \
  float n1_ = MED3(A0, A1, c);           \
  float n2_ = MED3(A1, A2, c);           \
  float n3_ = MED3(A2, A3, c);           \
  A0 = n0_; A1 = n1_; A2 = n2_; A3 = n3_; }

__device__ __forceinline__ unsigned long long pack_key(float a, int j) {
  unsigned u = __float_as_uint(a);
  unsigned ord = u ^ (unsigned)(((int)u >> 31) | 0x80000000);
  unsigned m = ~ord;                      // ascending m <-> descending acc <-> ascending d
  return ((unsigned long long)m << 32) | (unsigned)j;
}

// ---------------- Kernel P: f16 hi/lo fragments + (-sq/2) + init buffers ----------------
// 256 blocks x 64 threads: spread over all CUs (was 64x256 -> only 64 CUs active).
__global__ __launch_bounds__(64) void k_prep(
    const float* __restrict__ x, float4* __restrict__ fragHi,
    float4* __restrict__ fragLo, float* __restrict__ nsq,
    unsigned* __restrict__ gcnt, unsigned long long* __restrict__ gbuf,
    unsigned* __restrict__ bcnt)
{
  int p = blockIdx.x * 64 + threadIdx.x;
  const float4* xp = (const float4*)(x + (size_t)p * 32);
  int tile = p >> 4, lb = p & 15;
  float sq = 0.f;
  #pragma unroll
  for (int g = 0; g < 4; ++g) {
    float4 va = xp[g * 2], vb = xp[g * 2 + 1];
    float f[8] = {va.x, va.y, va.z, va.w, vb.x, vb.y, vb.z, vb.w};
    H8 hh, hl;
    #pragma unroll
    for (int e = 0; e < 8; ++e) {
      sq = fmaf(f[e], f[e], sq);
      _Float16 hi = (_Float16)f[e];
      _Float16 lo = (_Float16)(f[e] - (float)hi);
      hh.h[e] = hi; hl.h[e] = lo;
    }
    int a = tile * 64 + g * 16 + lb;
    fragHi[a] = hh.f; fragLo[a] = hl.f;
  }
  nsq[p] = -0.5f * sq;
  gcnt[p] = 0u;
  #pragma unroll
  for (int e = 0; e < NS; ++e) gbuf[(size_t)p * NS + e] = ~0ull;
  if (blockIdx.x == 0 && threadIdx.x < NCHUNK) bcnt[threadIdx.x] = 0u;
}

// ---- Pass A: per-(row,chunk) CHUNK-MAX only. 64 i-groups x 4 strips, 8 blocks/CU. ----
__global__ __launch_bounds__(256, 4) void k_knnA(
    const float4* __restrict__ fragHi, const float4* __restrict__ fragLo,
    const float* __restrict__ nsq, float* __restrict__ cvals)
{
  __shared__ half8 sHi[SUBT * 64];
  __shared__ half8 sLo[SUBT * 64];
  __shared__ float sNq[SUBT * 16];

  const int tid = threadIdx.x;
  const int w = tid >> 6, lane = tid & 63;
  const int grp = lane >> 4, col = lane & 15;
  const int cy = blockIdx.y;
  const int itbase = blockIdx.x * 16 + w * 4;      // 4 i-tile strips per wave
  const bool blkdiag = ((int)(blockIdx.x >> 1) == cy);  // i-range intersects chunk's j-range

  const half8* fH8 = (const half8*)fragHi;
  const half8* fL8 = (const half8*)fragLo;

  half8 bh[4], bl[4];
  #pragma unroll
  for (int s = 0; s < 4; ++s) {
    bh[s] = fH8[(size_t)(itbase + s) * 64 + lane];
    bl[s] = fL8[(size_t)(itbase + s) * 64 + lane];
  }
  const bool dg0 = (col == grp * 4 + 0), dg1 = (col == grp * 4 + 1);
  const bool dg2 = (col == grp * 4 + 2), dg3 = (col == grp * 4 + 3);

  float La1[4];
  #pragma unroll
  for (int s = 0; s < 4; ++s) La1[s] = -3.4e38f;

  for (int sc = 0; sc < NSUB; ++sc) {
    int jt0 = cy * JT_CH + sc * SUBT;
    __syncthreads();
    const float4* gH = fragHi + (size_t)jt0 * 64;
    const float4* gL = fragLo + (size_t)jt0 * 64;
    float4* dH = (float4*)sHi;
    float4* dL = (float4*)sLo;
    #pragma unroll
    for (int r = 0; r < 2; ++r) {
      dH[tid + r * 256] = gH[tid + r * 256];
      dL[tid + r * 256] = gL[tid + r * 256];
    }
    if (tid < SUBT * 16) sNq[tid] = nsq[jt0 * 16 + tid];
    __syncthreads();

    for (int t = 0; t < SUBT; ++t) {
      half8 ah = sHi[t * 64 + lane];
      half8 al = sLo[t * 64 + lane];
      f32x4 q = *(const f32x4*)&sNq[t * 16 + grp * 4];
      int jt = jt0 + t;
      #pragma unroll
      for (int s = 0; s < 4; ++s) {
        f32x4 acc = __builtin_amdgcn_mfma_f32_16x16x32_f16(ah, bh[s], q, 0, 0, 0);
        acc = __builtin_amdgcn_mfma_f32_16x16x32_f16(ah, bl[s], acc, 0, 0, 0);
        acc = __builtin_amdgcn_mfma_f32_16x16x32_f16(al, bh[s], acc, 0, 0, 0);
        if (blkdiag && jt == itbase + s) {         // diagonal tile: exclude j==i
          acc.x = dg0 ? -3.4e38f : acc.x;
          acc.y = dg1 ? -3.4e38f : acc.y;
          acc.z = dg2 ? -3.4e38f : acc.z;
          acc.w = dg3 ? -3.4e38f : acc.w;
        }
        // 2x v_max3_f32
        float t3 = fmaxf(fmaxf(acc.x, acc.y), acc.z);
        La1[s] = fmaxf(fmaxf(t3, acc.w), La1[s]);
      }
    }
  }

  #pragma unroll
  for (int s = 0; s < 4; ++s) {
    float m = La1[s];
    m = fmaxf(m, __shfl_xor(m, 16));
    m = fmaxf(m, __shfl_xor(m, 32));
    if (grp == 0) {
      int row = (itbase + s) * 16 + col;
      cvals[(size_t)cy * N_PTS + row] = m;     // chunk-major, coalesced
    }
  }
}

// ---- tau' + worklist: 4th-largest chunk-max per row; bucket chunks with cmax >= tau' ----
__global__ __launch_bounds__(128) void k_tauwl(
    const float* __restrict__ cvals, float* __restrict__ tau,
    unsigned* __restrict__ bcnt, int* __restrict__ bucket)
{
  __shared__ unsigned lcnt[NCHUNK];
  __shared__ unsigned gbase[NCHUNK];
  __shared__ int stage[NCHUNK][64];
  __shared__ float4 sL[64];
  __shared__ float sT[64];

  const int tid = threadIdx.x;
  const int lrow = tid & 63, half = tid >> 6;
  const int row = blockIdx.x * 64 + lrow;
  if (tid < NCHUNK) lcnt[tid] = 0u;
  __syncthreads();

  float A0 = -3.4e38f, A1 = -3.4e38f, A2 = -3.4e38f, A3 = -3.4e38f;
  float cm[16];
  #pragma unroll
  for (int k = 0; k < 16; ++k) {
    cm[k] = cvals[(size_t)(half * 16 + k) * N_PTS + row];  // coalesced
    INS4(cm[k], A0, A1, A2, A3);
  }
  if (half == 1) sL[lrow] = make_float4(A0, A1, A2, A3);
  __syncthreads();
  if (half == 0) {
    float4 o = sL[lrow];
    INS4(o.x, A0, A1, A2, A3);
    INS4(o.y, A0, A1, A2, A3);
    INS4(o.z, A0, A1, A2, A3);
    INS4(o.w, A0, A1, A2, A3);
    sT[lrow] = A3;
    tau[row] = A3;
  }
  __syncthreads();
  const float tt = sT[lrow];
  #pragma unroll
  for (int k = 0; k < 16; ++k) {
    if (cm[k] >= tt) {                          // chunk may hold a global top-4 member
      int c = half * 16 + k;
      unsigned p = atomicAdd(&lcnt[c], 1u);     // LDS atomic
      stage[c][p] = row;
    }
  }
  __syncthreads();
  if (tid < NCHUNK) gbase[tid] = atomicAdd(bcnt + tid, lcnt[tid]);
  __syncthreads();
  for (int c = 0; c < NCHUNK; ++c) {
    unsigned n = lcnt[c], gb = gbase[c];
    for (unsigned k = tid; k < n; k += 128)
      bucket[c * N_PTS + gb + k] = stage[c][k];
  }
}

// ---- Pass B (worklist): compact grid (32 x 32), block grid-strides over slices ----
__global__ __launch_bounds__(256) void k_knnBW(
    const float4* __restrict__ fragHi, const float4* __restrict__ fragLo,
    const float* __restrict__ nsq, const float* __restrict__ tau,
    const unsigned* __restrict__ bcnt, const int* __restrict__ bucket,
    unsigned* __restrict__ gcnt, unsigned long long* __restrict__ gbuf)
{
  const int c = blockIdx.x;
  const unsigned n = bcnt[c];
  const unsigned nslices = (n + 63u) >> 6;

  __shared__ int   sRow[64];
  __shared__ float sTau[64];

  const int tid = threadIdx.x;
  const int w = tid >> 6, lane = tid & 63;
  const int grp = lane >> 4, col = lane & 15;
  const float INF = __int_as_float(0x7f800000);

  const half8* fH8 = (const half8*)fragHi;
  const half8* fL8 = (const half8*)fragLo;

  for (unsigned ys = blockIdx.y; ys < nslices; ys += YSTRIDE) {
    const unsigned base = ys * 64u;
    if (tid < 64) {
      unsigned idx = base + tid;
      int myrow = (idx < n) ? bucket[c * N_PTS + idx] : -1;
      sRow[tid] = myrow;
      sTau[tid] = (myrow >= 0) ? tau[myrow] : INF;
    }
    __syncthreads();

    half8 bh[4], bl[4];
    int   rS[4];
    float tS[4];
    #pragma unroll
    for (int s = 0; s < 4; ++s) {
      int r = sRow[s * 16 + col];
      rS[s] = r;
      tS[s] = sTau[s * 16 + col];
      int rr = r < 0 ? 0 : r;
      size_t a = (size_t)(rr >> 4) * 64 + grp * 16 + (rr & 15);
      bh[s] = fH8[a];
      bl[s] = fL8[a];
    }

    // wave w handles j-tiles [c*32 + w*8, c*32 + (w+1)*8)
    const int jt0 = c * JT_CH + w * (JT_CH / 4);
    #pragma unroll 2
    for (int ti = 0; ti < JT_CH / 4; ++ti) {
      int jt = jt0 + ti;
      half8 ah = fH8[(size_t)jt * 64 + lane];
      half8 al = fL8[(size_t)jt * 64 + lane];
      f32x4 q = *(const f32x4*)&nsq[jt * 16 + grp * 4];
      #pragma unroll
      for (int s = 0; s < 4; ++s) {
        f32x4 acc = __builtin_amdgcn_mfma_f32_16x16x32_f16(ah, bh[s], q, 0, 0, 0);
        acc = __builtin_amdgcn_mfma_f32_16x16x32_f16(ah, bl[s], acc, 0, 0, 0);
        acc = __builtin_amdgcn_mfma_f32_16x16x32_f16(al, bh[s], acc, 0, 0, 0);
        int jbase = jt * 16 + grp * 4;
        acc.x = (jbase + 0 == rS[s]) ? -3.4e38f : acc.x;
        acc.y = (jbase + 1 == rS[s]) ? -3.4e38f : acc.y;
        acc.z = (jbase + 2 == rS[s]) ? -3.4e38f : acc.z;
        acc.w = (jbase + 3 == rS[s]) ? -3.4e38f : acc.w;
        float m = fmaxf(fmaxf(acc.x, acc.y), fmaxf(acc.z, acc.w));
        if (__ballot(m >= tS[s])) {
          float av[4] = {acc.x, acc.y, acc.z, acc.w};
          #pragma unroll
          for (int e = 0; e < 4; ++e) {
            if (av[e] >= tS[s]) {
              unsigned sl = atomicAdd(gcnt + rS[s], 1u);
              if (sl < (unsigned)NS) gbuf[(size_t)rS[s] * NS + sl] = pack_key(av[e], jbase + e);
            }
          }
        }
      }
    }
    __syncthreads();   // protect sRow/sTau before next slice's overwrite
  }
}

// ---- h = x @ gat_w + logits. LDS-FREE: gw column in regs, x row via uniform loads. ----
__global__ __launch_bounds__(256) void k_feat(
    const float* __restrict__ x, const float* __restrict__ gw,
    const float* __restrict__ aw_s, const float* __restrict__ aw_d,
    float* __restrict__ h, float* __restrict__ asrc, float* __restrict__ adst)
{
  const int tid = threadIdx.x;
  const int d = tid & 127, half = tid >> 7;      // wave-uniform half (waves 0,1 / 2,3)
  const int head = d >> 5, hid = d & 31;

  float gwr[32];
  #pragma unroll
  for (int k = 0; k < 32; ++k) gwr[k] = gw[k * 128 + d];   // coalesced across d
  const float ws_ = aw_s[head * 32 + hid], wd_ = aw_d[head * 32 + hid];

  #pragma unroll
  for (int p = 0; p < 8; ++p) {
    int nl = (p << 1) | half;                    // wave-uniform node
    int n = blockIdx.x * 16 + nl;
    const float4* xr = (const float4*)(x + (size_t)n * 32);  // uniform address
    float acc = 0.f;
    #pragma unroll
    for (int r = 0; r < 8; ++r) {
      float4 v = xr[r];
      acc = fmaf(v.x, gwr[r * 4 + 0], acc);
      acc = fmaf(v.y, gwr[r * 4 + 1], acc);
      acc = fmaf(v.z, gwr[r * 4 + 2], acc);
      acc = fmaf(v.w, gwr[r * 4 + 3], acc);
    }
    h[(size_t)n * 128 + d] = acc;
    float ps = acc * ws_, pd = acc * wd_;
    #pragma unroll
    for (int off = 16; off; off >>= 1) {
      ps += __shfl_xor(ps, off, 32);
      pd += __shfl_xor(pd, off, 32);
    }
    if (hid == 0) { asrc[n * 4 + head] = ps; adst[n * 4 + head] = pd; }
  }
}

// -------- GAT + ELU + partial batch mean (16 nodes/block, 4 partials per batch) --------
__global__ __launch_bounds__(256) void k_gat(
    const float* __restrict__ h, const float* __restrict__ asrc, const float* __restrict__ adst,
    const unsigned long long* __restrict__ gbuf, const float* __restrict__ gb,
    float* __restrict__ mo_part)
{
  int b2 = blockIdx.x;                 // 1024 blocks: batch b = b2>>2, quarter qq = b2&3
  int b = b2 >> 2, qq = b2 & 3;
  int tid = threadIdx.x;
  __shared__ int4 sknn[16];
  if (tid < 16) {
    int row = b * 64 + qq * 16 + tid;
    unsigned long long K0 = ~0ull, K1 = ~0ull, K2 = ~0ull, K3 = ~0ull;
    const unsigned long long* src = gbuf + (size_t)row * NS;
    #pragma unroll
    for (int e = 0; e < NS; ++e) {
      unsigned long long cc = src[e];
      bool g = cc < K3, c0 = cc < K0, c1 = cc < K1, c2 = cc < K2;
      unsigned long long n1 = c0 ? K0 : (c1 ? cc : K1);
      unsigned long long n2 = c1 ? K1 : (c2 ? cc : K2);
      unsigned long long n3 = c2 ? K2 : (g ? cc : K3);
      K0 = c0 ? cc : K0; K1 = n1; K2 = n2; K3 = n3;
    }
    sknn[tid] = make_int4((int)(unsigned)K0, (int)(unsigned)K1,
                          (int)(unsigned)K2, (int)(unsigned)K3);
  }
  __syncthreads();

  int w = tid >> 6, lane = tid & 63;
  int da = lane, db = lane + 64;
  int ha = lane >> 5, hb = ha + 2;
  float acca = 0.f, accb = 0.f;

  #pragma unroll
  for (int t = 0; t < 4; ++t) {
    int nl = t * 4 + w;
    int n = b * 64 + qq * 16 + nl;
    int4 nb = sknn[nl];
    int nbs[5] = {nb.x, nb.y, nb.z, nb.w, n};
    float ad_a = adst[n * 4 + ha], ad_b = adst[n * 4 + hb];
    float ea[5], eb[5];
    #pragma unroll
    for (int k = 0; k < 5; ++k) {
      float va = ad_a + asrc[nbs[k] * 4 + ha];
      float vb = ad_b + asrc[nbs[k] * 4 + hb];
      ea[k] = va > 0.f ? va : 0.2f * va;
      eb[k] = vb > 0.f ? vb : 0.2f * vb;
    }
    float ma = ea[0], mb = eb[0];
    #pragma unroll
    for (int k = 1; k < 5; ++k) { ma = fmaxf(ma, ea[k]); mb = fmaxf(mb, eb[k]); }
    float sa = 0.f, sb = 0.f;
    #pragma unroll
    for (int k = 0; k < 5; ++k) {
      ea[k] = __expf(ea[k] - ma); sa += ea[k];
      eb[k] = __expf(eb[k] - mb); sb += eb[k];
    }
    float outa = 0.f, outb = 0.f;
    #pragma unroll
    for (int k = 0; k < 5; ++k) {
      const float* hr = h + (size_t)nbs[k] * 128;
      outa = fmaf(ea[k], hr[da], outa);
      outb = fmaf(eb[k], hr[db], outb);
    }
    outa = outa / sa + gb[da];
    outb = outb / sb + gb[db];
    acca += outa > 0.f ? outa : expm1f(outa);
    accb += outb > 0.f ? outb : expm1f(outb);
  }

  __shared__ float red[4][128];
  red[w][da] = acca; red[w][db] = accb;
  __syncthreads();
  if (tid < 128) {
    float s = (red[0][tid] + red[1][tid] + red[2][tid] + red[3][tid]) * (1.f / 64.f);
    mo_part[b2 * 128 + tid] = s;
  }
}

// ---------------- final FC 128 -> 2 (sums the 4 mean partials) ----------------
__global__ __launch_bounds__(64) void k_fc(
    const float* __restrict__ mo_part, const float* __restrict__ fw, const float* __restrict__ fb,
    float* __restrict__ out)
{
  int b = blockIdx.x, lane = threadIdx.x;
  float m0 = 0.f, m1 = 0.f;
  #pragma unroll
  for (int q = 0; q < 4; ++q) {
    m0 += mo_part[(b * 4 + q) * 128 + lane];
    m1 += mo_part[(b * 4 + q) * 128 + lane + 64];
  }
  float p0 = m0 * fw[lane * 2]     + m1 * fw[(lane + 64) * 2];
  float p1 = m0 * fw[lane * 2 + 1] + m1 * fw[(lane + 64) * 2 + 1];
  #pragma unroll
  for (int off = 32; off; off >>= 1) {
    p0 += __shfl_xor(p0, off, 64);
    p1 += __shfl_xor(p1, off, 64);
  }
  if (lane == 0) { out[b * 2] = p0 + fb[0]; out[b * 2 + 1] = p1 + fb[1]; }
}

extern "C" void kernel_launch(void* const* d_in, const int* in_sizes, int n_in,
                              void* d_out, int out_size, void* d_ws, size_t ws_size,
                              hipStream_t stream)
{
  const float* x   = (const float*)d_in[0];
  // d_in[1..4] = edge-MLP weights: dead code in the reference output, skipped.
  const float* gw  = (const float*)d_in[5];
  const float* as_ = (const float*)d_in[6];
  const float* ad_ = (const float*)d_in[7];
  const float* gb  = (const float*)d_in[8];
  const float* fw  = (const float*)d_in[9];
  const float* fb  = (const float*)d_in[10];

  char* ws = (char*)d_ws;
  float*  cvals  = (float*)(ws);                         // 2 MB
  float*  h      = (float*)(ws + 2097152);               // 8 MB
  float*  asrc   = (float*)(ws + 10485760);              // 256 KB
  float*  adst   = (float*)(ws + 10747904);              // 256 KB
  float4* fragHi = (float4*)(ws + 11010048);             // 1 MB
  float4* fragLo = (float4*)(ws + 12058624);             // 1 MB
  float*  nsq    = (float*)(ws + 13107200);              // 64 KB
  float*  tau    = (float*)(ws + 13172736);              // 64 KB
  unsigned* gcnt = (unsigned*)(ws + 13238272);           // 64 KB
  unsigned long long* gbuf = (unsigned long long*)(ws + 13303808); // 2 MB
  unsigned* bcnt = (unsigned*)(ws + 15400960);           // 256 B
  int*    bucket = (int*)   (ws + 15401216);             // 2 MB
  float*  mo_part= (float*)(ws + 17498368);              // 512 KB
  float*  outp   = (float*)d_out;

  k_prep<<<256, 64, 0, stream>>>(x, fragHi, fragLo, nsq, gcnt, gbuf, bcnt);
  k_knnA<<<dim3(64, NCHUNK), 256, 0, stream>>>(fragHi, fragLo, nsq, cvals);
  k_tauwl<<<N_PTS / 64, 128, 0, stream>>>(cvals, tau, bcnt, bucket);
  k_knnBW<<<dim3(NCHUNK, YSTRIDE), 256, 0, stream>>>(fragHi, fragLo, nsq, tau,
                                                     bcnt, bucket, gcnt, gbuf);
  k_feat<<<N_PTS / 16, 256, 0, stream>>>(x, gw, as_, ad_, h, asrc, adst);
  k_gat<<<1024, 256, 0, stream>>>(h, asrc, adst, gbuf, gb, mo_part);
  k_fc<<<256, 64, 0, stream>>>(mo_part, fw, fb, outp);
}

// Round 20
// 116.947 us; speedup vs baseline: 1.0025x; 1.0025x over previous
//
#include <hip/hip_runtime.h>
#include <math.h>

#define N_PTS   16384
#define NT      1024         // 16-point tiles
#define NCHUNK  32
#define JT_CH   (NT/NCHUNK)  // 32 j-tiles per chunk
#define SUBT    8            // tiles per LDS staging round (16.9 KB -> 8 blocks/CU)
#define NSUB    (JT_CH/SUBT) // 4
#define NS      16           // gbuf slots per row
#define YSTRIDE 64           // pass-B y-blocks per chunk

typedef __attribute__((ext_vector_type(4))) float f32x4;
typedef __attribute__((ext_vector_type(8))) _Float16 half8;

union H8 { half8 h; float4 f; };

#define MED3(a,b,c) __builtin_amdgcn_fmed3f((a),(b),(c))

// branch-free exact top-4 (desc) insert: 1 max + 3 med3, ALL INDEPENDENT (1 dep level)
#define INS4(c, A0, A1, A2, A3) {        \
  float n0_ = fmaxf(A0, c);              \
  float n1_ = MED3(A0, A1, c);           \
  float n2_ = MED3(A1, A2, c);           \
  float n3_ = MED3(A2, A3, c);           \
  A0 = n0_; A1 = n1_; A2 = n2_; A3 = n3_; }

__device__ __forceinline__ unsigned long long pack_key(float a, int j) {
  unsigned u = __float_as_uint(a);
  unsigned ord = u ^ (unsigned)(((int)u >> 31) | 0x80000000);
  unsigned m = ~ord;                      // ascending m <-> descending acc <-> ascending d
  return ((unsigned long long)m << 32) | (unsigned)j;
}

// ---------------- Kernel P: f16 hi/lo fragments + (-sq/2) + init buffers ----------------
__global__ __launch_bounds__(64) void k_prep(
    const float* __restrict__ x, float4* __restrict__ fragHi,
    float4* __restrict__ fragLo, float* __restrict__ nsq,
    unsigned* __restrict__ gcnt, unsigned long long* __restrict__ gbuf,
    unsigned* __restrict__ bcnt)
{
  int p = blockIdx.x * 64 + threadIdx.x;
  const float4* xp = (const float4*)(x + (size_t)p * 32);
  int tile = p >> 4, lb = p & 15;
  float sq = 0.f;
  #pragma unroll
  for (int g = 0; g < 4; ++g) {
    float4 va = xp[g * 2], vb = xp[g * 2 + 1];
    float f[8] = {va.x, va.y, va.z, va.w, vb.x, vb.y, vb.z, vb.w};
    H8 hh, hl;
    #pragma unroll
    for (int e = 0; e < 8; ++e) {
      sq = fmaf(f[e], f[e], sq);
      _Float16 hi = (_Float16)f[e];
      _Float16 lo = (_Float16)(f[e] - (float)hi);
      hh.h[e] = hi; hl.h[e] = lo;
    }
    int a = tile * 64 + g * 16 + lb;
    fragHi[a] = hh.f; fragLo[a] = hl.f;
  }
  nsq[p] = -0.5f * sq;
  gcnt[p] = 0u;
  #pragma unroll
  for (int e = 0; e < NS; ++e) gbuf[(size_t)p * NS + e] = ~0ull;
  if (blockIdx.x == 0 && threadIdx.x < NCHUNK) bcnt[threadIdx.x] = 0u;
}

// ---- Pass A: per-(row,chunk) CHUNK-MAX only. 64 i-groups x 4 strips, 8 blocks/CU. ----
__global__ __launch_bounds__(256, 4) void k_knnA(
    const float4* __restrict__ fragHi, const float4* __restrict__ fragLo,
    const float* __restrict__ nsq, float* __restrict__ cvals)
{
  __shared__ half8 sHi[SUBT * 64];
  __shared__ half8 sLo[SUBT * 64];
  __shared__ float sNq[SUBT * 16];

  const int tid = threadIdx.x;
  const int w = tid >> 6, lane = tid & 63;
  const int grp = lane >> 4, col = lane & 15;
  const int cy = blockIdx.y;
  const int itbase = blockIdx.x * 16 + w * 4;      // 4 i-tile strips per wave
  const bool blkdiag = ((int)(blockIdx.x >> 1) == cy);  // i-range intersects chunk's j-range

  const half8* fH8 = (const half8*)fragHi;
  const half8* fL8 = (const half8*)fragLo;

  half8 bh[4], bl[4];
  #pragma unroll
  for (int s = 0; s < 4; ++s) {
    bh[s] = fH8[(size_t)(itbase + s) * 64 + lane];
    bl[s] = fL8[(size_t)(itbase + s) * 64 + lane];
  }
  const bool dg0 = (col == grp * 4 + 0), dg1 = (col == grp * 4 + 1);
  const bool dg2 = (col == grp * 4 + 2), dg3 = (col == grp * 4 + 3);

  float La1[4];
  #pragma unroll
  for (int s = 0; s < 4; ++s) La1[s] = -3.4e38f;

  for (int sc = 0; sc < NSUB; ++sc) {
    int jt0 = cy * JT_CH + sc * SUBT;
    __syncthreads();
    const float4* gH = fragHi + (size_t)jt0 * 64;
    const float4* gL = fragLo + (size_t)jt0 * 64;
    float4* dH = (float4*)sHi;
    float4* dL = (float4*)sLo;
    #pragma unroll
    for (int r = 0; r < 2; ++r) {
      dH[tid + r * 256] = gH[tid + r * 256];
      dL[tid + r * 256] = gL[tid + r * 256];
    }
    if (tid < SUBT * 16) sNq[tid] = nsq[jt0 * 16 + tid];
    __syncthreads();

    for (int t = 0; t < SUBT; ++t) {
      half8 ah = sHi[t * 64 + lane];
      half8 al = sLo[t * 64 + lane];
      f32x4 q = *(const f32x4*)&sNq[t * 16 + grp * 4];
      int jt = jt0 + t;
      #pragma unroll
      for (int s = 0; s < 4; ++s) {
        f32x4 acc = __builtin_amdgcn_mfma_f32_16x16x32_f16(ah, bh[s], q, 0, 0, 0);
        acc = __builtin_amdgcn_mfma_f32_16x16x32_f16(ah, bl[s], acc, 0, 0, 0);
        acc = __builtin_amdgcn_mfma_f32_16x16x32_f16(al, bh[s], acc, 0, 0, 0);
        if (blkdiag && jt == itbase + s) {         // diagonal tile: exclude j==i
          acc.x = dg0 ? -3.4e38f : acc.x;
          acc.y = dg1 ? -3.4e38f : acc.y;
          acc.z = dg2 ? -3.4e38f : acc.z;
          acc.w = dg3 ? -3.4e38f : acc.w;
        }
        // 2x v_max3_f32
        float t3 = fmaxf(fmaxf(acc.x, acc.y), acc.z);
        La1[s] = fmaxf(fmaxf(t3, acc.w), La1[s]);
      }
    }
  }

  #pragma unroll
  for (int s = 0; s < 4; ++s) {
    float m = La1[s];
    m = fmaxf(m, __shfl_xor(m, 16));
    m = fmaxf(m, __shfl_xor(m, 32));
    if (grp == 0) {
      int row = (itbase + s) * 16 + col;
      cvals[(size_t)cy * N_PTS + row] = m;     // chunk-major, coalesced
    }
  }
}

// ---- tau' + worklist: 4th-largest chunk-max per row; bucket chunks with cmax >= tau' ----
__global__ __launch_bounds__(128) void k_tauwl(
    const float* __restrict__ cvals, float* __restrict__ tau,
    unsigned* __restrict__ bcnt, int* __restrict__ bucket)
{
  __shared__ unsigned lcnt[NCHUNK];
  __shared__ unsigned gbase[NCHUNK];
  __shared__ int stage[NCHUNK][64];
  __shared__ float4 sL[64];
  __shared__ float sT[64];

  const int tid = threadIdx.x;
  const int lrow = tid & 63, half = tid >> 6;
  const int row = blockIdx.x * 64 + lrow;
  if (tid < NCHUNK) lcnt[tid] = 0u;
  __syncthreads();

  float A0 = -3.4e38f, A1 = -3.4e38f, A2 = -3.4e38f, A3 = -3.4e38f;
  float cm[16];
  #pragma unroll
  for (int k = 0; k < 16; ++k) {
    cm[k] = cvals[(size_t)(half * 16 + k) * N_PTS + row];  // coalesced
    INS4(cm[k], A0, A1, A2, A3);
  }
  if (half == 1) sL[lrow] = make_float4(A0, A1, A2, A3);
  __syncthreads();
  if (half == 0) {
    float4 o = sL[lrow];
    INS4(o.x, A0, A1, A2, A3);
    INS4(o.y, A0, A1, A2, A3);
    INS4(o.z, A0, A1, A2, A3);
    INS4(o.w, A0, A1, A2, A3);
    sT[lrow] = A3;
    tau[row] = A3;
  }
  __syncthreads();
  const float tt = sT[lrow];
  #pragma unroll
  for (int k = 0; k < 16; ++k) {
    if (cm[k] >= tt) {                          // chunk may hold a global top-4 member
      int c = half * 16 + k;
      unsigned p = atomicAdd(&lcnt[c], 1u);     // LDS atomic
      stage[c][p] = row;
    }
  }
  __syncthreads();
  if (tid < NCHUNK) gbase[tid] = atomicAdd(bcnt + tid, lcnt[tid]);
  __syncthreads();
  for (int c = 0; c < NCHUNK; ++c) {
    unsigned n = lcnt[c], gb = gbase[c];
    for (unsigned k = tid; k < n; k += 128)
      bucket[c * N_PTS + gb + k] = stage[c][k];
  }
}

// ---- Pass B (worklist): grid (32 x 64) = 2048 blocks, stride over slices ----
__global__ __launch_bounds__(256) void k_knnBW(
    const float4* __restrict__ fragHi, const float4* __restrict__ fragLo,
    const float* __restrict__ nsq, const float* __restrict__ tau,
    const unsigned* __restrict__ bcnt, const int* __restrict__ bucket,
    unsigned* __restrict__ gcnt, unsigned long long* __restrict__ gbuf)
{
  const int c = blockIdx.x;
  const unsigned n = bcnt[c];
  const unsigned nslices = (n + 63u) >> 6;

  __shared__ int   sRow[64];
  __shared__ float sTau[64];

  const int tid = threadIdx.x;
  const int w = tid >> 6, lane = tid & 63;
  const int grp = lane >> 4, col = lane & 15;
  const float INF = __int_as_float(0x7f800000);

  const half8* fH8 = (const half8*)fragHi;
  const half8* fL8 = (const half8*)fragLo;

  for (unsigned ys = blockIdx.y; ys < nslices; ys += YSTRIDE) {
    const unsigned base = ys * 64u;
    if (tid < 64) {
      unsigned idx = base + tid;
      int myrow = (idx < n) ? bucket[c * N_PTS + idx] : -1;
      sRow[tid] = myrow;
      sTau[tid] = (myrow >= 0) ? tau[myrow] : INF;
    }
    __syncthreads();

    half8 bh[4], bl[4];
    int   rS[4];
    float tS[4];
    #pragma unroll
    for (int s = 0; s < 4; ++s) {
      int r = sRow[s * 16 + col];
      rS[s] = r;
      tS[s] = sTau[s * 16 + col];
      int rr = r < 0 ? 0 : r;
      size_t a = (size_t)(rr >> 4) * 64 + grp * 16 + (rr & 15);
      bh[s] = fH8[a];
      bl[s] = fL8[a];
    }

    // wave w handles j-tiles [c*32 + w*8, c*32 + (w+1)*8)
    const int jt0 = c * JT_CH + w * (JT_CH / 4);
    #pragma unroll 2
    for (int ti = 0; ti < JT_CH / 4; ++ti) {
      int jt = jt0 + ti;
      half8 ah = fH8[(size_t)jt * 64 + lane];
      half8 al = fL8[(size_t)jt * 64 + lane];
      f32x4 q = *(const f32x4*)&nsq[jt * 16 + grp * 4];
      #pragma unroll
      for (int s = 0; s < 4; ++s) {
        f32x4 acc = __builtin_amdgcn_mfma_f32_16x16x32_f16(ah, bh[s], q, 0, 0, 0);
        acc = __builtin_amdgcn_mfma_f32_16x16x32_f16(ah, bl[s], acc, 0, 0, 0);
        acc = __builtin_amdgcn_mfma_f32_16x16x32_f16(al, bh[s], acc, 0, 0, 0);
        int jbase = jt * 16 + grp * 4;
        acc.x = (jbase + 0 == rS[s]) ? -3.4e38f : acc.x;
        acc.y = (jbase + 1 == rS[s]) ? -3.4e38f : acc.y;
        acc.z = (jbase + 2 == rS[s]) ? -3.4e38f : acc.z;
        acc.w = (jbase + 3 == rS[s]) ? -3.4e38f : acc.w;
        float m = fmaxf(fmaxf(acc.x, acc.y), fmaxf(acc.z, acc.w));
        if (__ballot(m >= tS[s])) {
          float av[4] = {acc.x, acc.y, acc.z, acc.w};
          #pragma unroll
          for (int e = 0; e < 4; ++e) {
            if (av[e] >= tS[s]) {
              unsigned sl = atomicAdd(gcnt + rS[s], 1u);
              if (sl < (unsigned)NS) gbuf[(size_t)rS[s] * NS + sl] = pack_key(av[e], jbase + e);
            }
          }
        }
      }
    }
    __syncthreads();   // protect sRow/sTau before next slice's overwrite
  }
}

// ---- h = x @ gat_w + logits. LDS-free; 8 nodes/block -> 2048 blocks (8/CU). ----
__global__ __launch_bounds__(256) void k_feat(
    const float* __restrict__ x, const float* __restrict__ gw,
    const float* __restrict__ aw_s, const float* __restrict__ aw_d,
    float* __restrict__ h, float* __restrict__ asrc, float* __restrict__ adst)
{
  const int tid = threadIdx.x;
  const int d = tid & 127, half = tid >> 7;      // wave-uniform half
  const int head = d >> 5, hid = d & 31;

  float gwr[32];
  #pragma unroll
  for (int k = 0; k < 32; ++k) gwr[k] = gw[k * 128 + d];   // coalesced across d
  const float ws_ = aw_s[head * 32 + hid], wd_ = aw_d[head * 32 + hid];

  #pragma unroll
  for (int p = 0; p < 4; ++p) {
    int nl = (p << 1) | half;                    // wave-uniform node 0..7
    int n = blockIdx.x * 8 + nl;
    const float4* xr = (const float4*)(x + (size_t)n * 32);  // uniform address
    float acc = 0.f;
    #pragma unroll
    for (int r = 0; r < 8; ++r) {
      float4 v = xr[r];
      acc = fmaf(v.x, gwr[r * 4 + 0], acc);
      acc = fmaf(v.y, gwr[r * 4 + 1], acc);
      acc = fmaf(v.z, gwr[r * 4 + 2], acc);
      acc = fmaf(v.w, gwr[r * 4 + 3], acc);
    }
    h[(size_t)n * 128 + d] = acc;
    float ps = acc * ws_, pd = acc * wd_;
    #pragma unroll
    for (int off = 16; off; off >>= 1) {
      ps += __shfl_xor(ps, off, 32);
      pd += __shfl_xor(pd, off, 32);
    }
    if (hid == 0) { asrc[n * 4 + head] = ps; adst[n * 4 + head] = pd; }
  }
}

// -------- GAT + ELU + partial batch mean: 8 nodes/block -> 2048 blocks, 8 partials --------
__global__ __launch_bounds__(256) void k_gat(
    const float* __restrict__ h, const float* __restrict__ asrc, const float* __restrict__ adst,
    const unsigned long long* __restrict__ gbuf, const float* __restrict__ gb,
    float* __restrict__ mo_part)
{
  int b2 = blockIdx.x;                 // 2048 blocks: batch b = b2>>3, octant oc = b2&7
  int b = b2 >> 3, oc = b2 & 7;
  int tid = threadIdx.x;
  __shared__ int4 sknn[8];
  if (tid < 8) {
    int row = b * 64 + oc * 8 + tid;
    unsigned long long K0 = ~0ull, K1 = ~0ull, K2 = ~0ull, K3 = ~0ull;
    const unsigned long long* src = gbuf + (size_t)row * NS;
    #pragma unroll
    for (int e = 0; e < NS; ++e) {
      unsigned long long cc = src[e];
      bool g = cc < K3, c0 = cc < K0, c1 = cc < K1, c2 = cc < K2;
      unsigned long long n1 = c0 ? K0 : (c1 ? cc : K1);
      unsigned long long n2 = c1 ? K1 : (c2 ? cc : K2);
      unsigned long long n3 = c2 ? K2 : (g ? cc : K3);
      K0 = c0 ? cc : K0; K1 = n1; K2 = n2; K3 = n3;
    }
    sknn[tid] = make_int4((int)(unsigned)K0, (int)(unsigned)K1,
                          (int)(unsigned)K2, (int)(unsigned)K3);
  }
  __syncthreads();

  int w = tid >> 6, lane = tid & 63;
  int da = lane, db = lane + 64;
  int ha = lane >> 5, hb = ha + 2;
  float acca = 0.f, accb = 0.f;

  #pragma unroll
  for (int t = 0; t < 2; ++t) {
    int nl = t * 4 + w;
    int n = b * 64 + oc * 8 + nl;
    int4 nb = sknn[nl];
    int nbs[5] = {nb.x, nb.y, nb.z, nb.w, n};
    float ad_a = adst[n * 4 + ha], ad_b = adst[n * 4 + hb];
    float ea[5], eb[5];
    #pragma unroll
    for (int k = 0; k < 5; ++k) {
      float va = ad_a + asrc[nbs[k] * 4 + ha];
      float vb = ad_b + asrc[nbs[k] * 4 + hb];
      ea[k] = va > 0.f ? va : 0.2f * va;
      eb[k] = vb > 0.f ? vb : 0.2f * vb;
    }
    float ma = ea[0], mb = eb[0];
    #pragma unroll
    for (int k = 1; k < 5; ++k) { ma = fmaxf(ma, ea[k]); mb = fmaxf(mb, eb[k]); }
    float sa = 0.f, sb = 0.f;
    #pragma unroll
    for (int k = 0; k < 5; ++k) {
      ea[k] = __expf(ea[k] - ma); sa += ea[k];
      eb[k] = __expf(eb[k] - mb); sb += eb[k];
    }
    float outa = 0.f, outb = 0.f;
    #pragma unroll
    for (int k = 0; k < 5; ++k) {
      const float* hr = h + (size_t)nbs[k] * 128;
      outa = fmaf(ea[k], hr[da], outa);
      outb = fmaf(eb[k], hr[db], outb);
    }
    outa = outa / sa + gb[da];
    outb = outb / sb + gb[db];
    acca += outa > 0.f ? outa : expm1f(outa);
    accb += outb > 0.f ? outb : expm1f(outb);
  }

  __shared__ float red[4][128];
  red[w][da] = acca; red[w][db] = accb;
  __syncthreads();
  if (tid < 128) {
    float s = (red[0][tid] + red[1][tid] + red[2][tid] + red[3][tid]) * (1.f / 64.f);
    mo_part[b2 * 128 + tid] = s;
  }
}

// ---------------- final FC 128 -> 2 (sums the 8 mean partials) ----------------
__global__ __launch_bounds__(64) void k_fc(
    const float* __restrict__ mo_part, const float* __restrict__ fw, const float* __restrict__ fb,
    float* __restrict__ out)
{
  int b = blockIdx.x, lane = threadIdx.x;
  float m0 = 0.f, m1 = 0.f;
  #pragma unroll
  for (int q = 0; q < 8; ++q) {
    m0 += mo_part[(b * 8 + q) * 128 + lane];
    m1 += mo_part[(b * 8 + q) * 128 + lane + 64];
  }
  float p0 = m0 * fw[lane * 2]     + m1 * fw[(lane + 64) * 2];
  float p1 = m0 * fw[lane * 2 + 1] + m1 * fw[(lane + 64) * 2 + 1];
  #pragma unroll
  for (int off = 32; off; off >>= 1) {
    p0 += __shfl_xor(p0, off, 64);
    p1 += __shfl_xor(p1, off, 64);
  }
  if (lane == 0) { out[b * 2] = p0 + fb[0]; out[b * 2 + 1] = p1 + fb[1]; }
}

extern "C" void kernel_launch(void* const* d_in, const int* in_sizes, int n_in,
                              void* d_out, int out_size, void* d_ws, size_t ws_size,
                              hipStream_t stream)
{
  const float* x   = (const float*)d_in[0];
  // d_in[1..4] = edge-MLP weights: dead code in the reference output, skipped.
  const float* gw  = (const float*)d_in[5];
  const float* as_ = (const float*)d_in[6];
  const float* ad_ = (const float*)d_in[7];
  const float* gb  = (const float*)d_in[8];
  const float* fw  = (const float*)d_in[9];
  const float* fb  = (const float*)d_in[10];

  char* ws = (char*)d_ws;
  float*  cvals  = (float*)(ws);                         // 2 MB
  float*  h      = (float*)(ws + 2097152);               // 8 MB
  float*  asrc   = (float*)(ws + 10485760);              // 256 KB
  float*  adst   = (float*)(ws + 10747904);              // 256 KB
  float4* fragHi = (float4*)(ws + 11010048);             // 1 MB
  float4* fragLo = (float4*)(ws + 12058624);             // 1 MB
  float*  nsq    = (float*)(ws + 13107200);              // 64 KB
  float*  tau    = (float*)(ws + 13172736);              // 64 KB
  unsigned* gcnt = (unsigned*)(ws + 13238272);           // 64 KB
  unsigned long long* gbuf = (unsigned long long*)(ws + 13303808); // 2 MB
  unsigned* bcnt = (unsigned*)(ws + 15400960);           // 256 B
  int*    bucket = (int*)   (ws + 15401216);             // 2 MB
  float*  mo_part= (float*)(ws + 17498368);              // 1 MB (2048*128*4)
  float*  outp   = (float*)d_out;

  k_prep<<<256, 64, 0, stream>>>(x, fragHi, fragLo, nsq, gcnt, gbuf, bcnt);
  k_knnA<<<dim3(64, NCHUNK), 256, 0, stream>>>(fragHi, fragLo, nsq, cvals);
  k_tauwl<<<N_PTS / 64, 128, 0, stream>>>(cvals, tau, bcnt, bucket);
  k_knnBW<<<dim3(NCHUNK, YSTRIDE), 256, 0, stream>>>(fragHi, fragLo, nsq, tau,
                                                     bcnt, bucket, gcnt, gbuf);
  k_feat<<<N_PTS / 8, 256, 0, stream>>>(x, gw, as_, ad_, h, asrc, adst);
  k_gat<<<2048, 256, 0, stream>>>(h, asrc, adst, gbuf, gb, mo_part);
  k_fc<<<256, 64, 0, stream>>>(mo_part, fw, fb, outp);
}

// Round 21
// 107.672 us; speedup vs baseline: 1.0889x; 1.0861x over previous
//
#include <hip/hip_runtime.h>
#include <math.h>

#define N_PTS   16384
#define NT      1024         // 16-point tiles
#define NCHUNK  32
#define JT_CH   (NT/NCHUNK)  // 32 j-tiles per chunk
#define SUBT    16           // tiles per LDS staging round (hi only: 17 KB)
#define NSUB    (JT_CH/SUBT) // 2
#define NS      16           // gbuf slots per row
#define JSPLIT  4            // pass-B j-segments per chunk

typedef __attribute__((ext_vector_type(4))) float f32x4;
typedef __attribute__((ext_vector_type(8))) _Float16 half8;

union H8 { half8 h; float4 f; };

#define MED3(a,b,c) __builtin_amdgcn_fmed3f((a),(b),(c))

// branch-free exact top-4 (desc) insert: 1 max + 3 med3, ALL INDEPENDENT (1 dep level)
#define INS4(c, A0, A1, A2, A3) {        \
  float n0_ = fmaxf(A0, c);              \
  float n1_ = MED3(A0, A1, c);           \
  float n2_ = MED3(A1, A2, c);           \
  float n3_ = MED3(A2, A3, c);           \
  A0 = n0_; A1 = n1_; A2 = n2_; A3 = n3_; }

__device__ __forceinline__ unsigned long long pack_key(float a, int j) {
  unsigned u = __float_as_uint(a);
  unsigned ord = u ^ (unsigned)(((int)u >> 31) | 0x80000000);
  unsigned m = ~ord;                      // ascending m <-> descending acc <-> ascending d
  return ((unsigned long long)m << 32) | (unsigned)j;
}

// ---------------- Kernel P: f16 hi/lo fragments + (-sq/2) + norm maxes + init ----------
__global__ __launch_bounds__(64) void k_prep(
    const float* __restrict__ x, float4* __restrict__ fragHi,
    float4* __restrict__ fragLo, float* __restrict__ nsq,
    unsigned* __restrict__ gcnt, unsigned long long* __restrict__ gbuf,
    unsigned* __restrict__ bcnt, float* __restrict__ nmx)
{
  int p = blockIdx.x * 64 + threadIdx.x;
  const float4* xp = (const float4*)(x + (size_t)p * 32);
  int tile = p >> 4, lb = p & 15;
  float sq = 0.f, hn2 = 0.f, ln2 = 0.f;
  #pragma unroll
  for (int g = 0; g < 4; ++g) {
    float4 va = xp[g * 2], vb = xp[g * 2 + 1];
    float f[8] = {va.x, va.y, va.z, va.w, vb.x, vb.y, vb.z, vb.w};
    H8 hh, hl;
    #pragma unroll
    for (int e = 0; e < 8; ++e) {
      sq = fmaf(f[e], f[e], sq);
      _Float16 hi = (_Float16)f[e];
      _Float16 lo = (_Float16)(f[e] - (float)hi);
      hh.h[e] = hi; hl.h[e] = lo;
      float hf = (float)hi, lf = (float)lo;
      hn2 = fmaf(hf, hf, hn2);
      ln2 = fmaf(lf, lf, ln2);
    }
    int a = tile * 64 + g * 16 + lb;
    fragHi[a] = hh.f; fragLo[a] = hl.f;
  }
  nsq[p] = -0.5f * sq;
  gcnt[p] = 0u;
  #pragma unroll
  for (int e = 0; e < NS; ++e) gbuf[(size_t)p * NS + e] = ~0ull;
  if (blockIdx.x == 0 && threadIdx.x < NCHUNK) bcnt[threadIdx.x] = 0u;

  // wave-reduce the squared-norm maxima, one atomic per wave (positive floats:
  // bit pattern is monotone, so uint atomicMax is float max)
  #pragma unroll
  for (int off = 32; off; off >>= 1) {
    hn2 = fmaxf(hn2, __shfl_xor(hn2, off));
    ln2 = fmaxf(ln2, __shfl_xor(ln2, off));
  }
  if (threadIdx.x == 0) {
    atomicMax((unsigned*)&nmx[0], __float_as_uint(hn2));
    atomicMax((unsigned*)&nmx[1], __float_as_uint(ln2));
  }
}

// ---- Pass A: per-(row,chunk) chunk-max of G = hi.hi + q  (SINGLE MFMA per tile-pair).
// G is bit-identical to the first partial of pass-B's F-chain; |F-G| <= EPS bound
// is applied in k_tauwl, keeping the gate exact.
__global__ __launch_bounds__(256, 4) void k_knnA(
    const float4* __restrict__ fragHi, const float* __restrict__ nsq,
    float* __restrict__ cvals)
{
  __shared__ half8 sHi[SUBT * 64];     // 16 KB
  __shared__ float sNq[SUBT * 16];     // 1 KB

  const int tid = threadIdx.x;
  const int w = tid >> 6, lane = tid & 63;
  const int grp = lane >> 4, col = lane & 15;
  const int cy = blockIdx.y;
  const int itbase = blockIdx.x * 16 + w * 4;      // 4 i-tile strips per wave
  const bool blkdiag = ((int)(blockIdx.x >> 1) == cy);

  const half8* fH8 = (const half8*)fragHi;

  half8 bh[4];
  #pragma unroll
  for (int s = 0; s < 4; ++s)
    bh[s] = fH8[(size_t)(itbase + s) * 64 + lane];
  const bool dg0 = (col == grp * 4 + 0), dg1 = (col == grp * 4 + 1);
  const bool dg2 = (col == grp * 4 + 2), dg3 = (col == grp * 4 + 3);

  float La1[4];
  #pragma unroll
  for (int s = 0; s < 4; ++s) La1[s] = -3.4e38f;

  for (int sc = 0; sc < NSUB; ++sc) {
    int jt0 = cy * JT_CH + sc * SUBT;
    __syncthreads();
    const float4* gH = fragHi + (size_t)jt0 * 64;
    float4* dH = (float4*)sHi;
    #pragma unroll
    for (int r = 0; r < 4; ++r)
      dH[tid + r * 256] = gH[tid + r * 256];
    sNq[tid] = nsq[jt0 * 16 + tid];
    __syncthreads();

    for (int t = 0; t < SUBT; ++t) {
      half8 ah = sHi[t * 64 + lane];
      f32x4 q = *(const f32x4*)&sNq[t * 16 + grp * 4];
      int jt = jt0 + t;
      #pragma unroll
      for (int s = 0; s < 4; ++s) {
        f32x4 acc = __builtin_amdgcn_mfma_f32_16x16x32_f16(ah, bh[s], q, 0, 0, 0);
        if (blkdiag && jt == itbase + s) {         // diagonal tile: exclude j==i
          acc.x = dg0 ? -3.4e38f : acc.x;
          acc.y = dg1 ? -3.4e38f : acc.y;
          acc.z = dg2 ? -3.4e38f : acc.z;
          acc.w = dg3 ? -3.4e38f : acc.w;
        }
        float t3 = fmaxf(fmaxf(acc.x, acc.y), acc.z);   // v_max3
        La1[s] = fmaxf(fmaxf(t3, acc.w), La1[s]);       // v_max3
      }
    }
  }

  #pragma unroll
  for (int s = 0; s < 4; ++s) {
    float m = La1[s];
    m = fmaxf(m, __shfl_xor(m, 16));
    m = fmaxf(m, __shfl_xor(m, 32));
    if (grp == 0) {
      int row = (itbase + s) * 16 + col;
      cvals[(size_t)cy * N_PTS + row] = m;     // chunk-major, coalesced
    }
  }
}

// ---- tau' + worklist: theta = (4th-largest G-chunk-max) - 2*EPS; bucket cmax >= theta ----
__global__ __launch_bounds__(128) void k_tauwl(
    const float* __restrict__ cvals, float* __restrict__ tau,
    unsigned* __restrict__ bcnt, int* __restrict__ bucket,
    const float* __restrict__ nmx)
{
  __shared__ unsigned lcnt[NCHUNK];
  __shared__ unsigned gbase[NCHUNK];
  __shared__ int stage[NCHUNK][64];
  __shared__ float4 sL[64];
  __shared__ float sT[64];

  const int tid = threadIdx.x;
  const int lrow = tid & 63, half = tid >> 6;
  const int row = blockIdx.x * 64 + lrow;
  if (tid < NCHUNK) lcnt[tid] = 0u;

  // 2*EPS with 1.1x safety + absolute slack for fp32 accumulation differences
  const float eps = 4.4f * sqrtf(nmx[0]) * sqrtf(nmx[1]) + 1e-3f;
  __syncthreads();

  float A0 = -3.4e38f, A1 = -3.4e38f, A2 = -3.4e38f, A3 = -3.4e38f;
  float cm[16];
  #pragma unroll
  for (int k = 0; k < 16; ++k) {
    cm[k] = cvals[(size_t)(half * 16 + k) * N_PTS + row];  // coalesced
    INS4(cm[k], A0, A1, A2, A3);
  }
  if (half == 1) sL[lrow] = make_float4(A0, A1, A2, A3);
  __syncthreads();
  if (half == 0) {
    float4 o = sL[lrow];
    INS4(o.x, A0, A1, A2, A3);
    INS4(o.y, A0, A1, A2, A3);
    INS4(o.z, A0, A1, A2, A3);
    INS4(o.w, A0, A1, A2, A3);
    float theta = A3 - eps;
    sT[lrow] = theta;
    tau[row] = theta;
  }
  __syncthreads();
  const float tt = sT[lrow];
  #pragma unroll
  for (int k = 0; k < 16; ++k) {
    if (cm[k] >= tt) {                          // chunk may hold a global top-4 member
      int c = half * 16 + k;
      unsigned p = atomicAdd(&lcnt[c], 1u);     // LDS atomic
      stage[c][p] = row;
    }
  }
  __syncthreads();
  if (tid < NCHUNK) gbase[tid] = atomicAdd(bcnt + tid, lcnt[tid]);
  __syncthreads();
  for (int c = 0; c < NCHUNK; ++c) {
    unsigned n = lcnt[c], gb = gbase[c];
    for (unsigned k = tid; k < n; k += 128)
      bucket[c * N_PTS + gb + k] = stage[c][k];
  }
}

// ---- Pass B (worklist): full F (3 MFMA), j-split 4-ways; emits F >= theta (exact) ----
__global__ __launch_bounds__(256) void k_knnBW(
    const float4* __restrict__ fragHi, const float4* __restrict__ fragLo,
    const float* __restrict__ nsq, const float* __restrict__ tau,
    const unsigned* __restrict__ bcnt, const int* __restrict__ bucket,
    unsigned* __restrict__ gcnt, unsigned long long* __restrict__ gbuf)
{
  const int c = blockIdx.x;
  const int jseg = blockIdx.y >> 8;
  const unsigned n = bcnt[c];
  const unsigned base = (unsigned)(blockIdx.y & 255) * 64;
  if (base >= n) return;

  __shared__ int   sRow[64];
  __shared__ float sTau[64];

  const int tid = threadIdx.x;
  const int w = tid >> 6, lane = tid & 63;
  const int grp = lane >> 4, col = lane & 15;
  const float INF = __int_as_float(0x7f800000);

  if (tid < 64) {
    unsigned idx = base + tid;
    int myrow = (idx < n) ? bucket[c * N_PTS + idx] : -1;
    sRow[tid] = myrow;
    sTau[tid] = (myrow >= 0) ? tau[myrow] : INF;
  }
  __syncthreads();

  const half8* fH8 = (const half8*)fragHi;
  const half8* fL8 = (const half8*)fragLo;

  half8 bh[4], bl[4];
  int   rS[4];
  float tS[4];
  #pragma unroll
  for (int s = 0; s < 4; ++s) {
    int r = sRow[s * 16 + col];
    rS[s] = r;
    tS[s] = sTau[s * 16 + col];
    int rr = r < 0 ? 0 : r;
    size_t a = (size_t)(rr >> 4) * 64 + grp * 16 + (rr & 15);
    bh[s] = fH8[a];
    bl[s] = fL8[a];
  }

  // wave w handles j-tiles jt0..jt0+1 (2 serial iterations)
  const int jt0 = c * JT_CH + jseg * (JT_CH / JSPLIT) + w * (JT_CH / (JSPLIT * 4));
  #pragma unroll
  for (int ti = 0; ti < JT_CH / (JSPLIT * 4); ++ti) {
    int jt = jt0 + ti;
    half8 ah = fH8[(size_t)jt * 64 + lane];
    half8 al = fL8[(size_t)jt * 64 + lane];
    f32x4 q = *(const f32x4*)&nsq[jt * 16 + grp * 4];
    #pragma unroll
    for (int s = 0; s < 4; ++s) {
      f32x4 acc = __builtin_amdgcn_mfma_f32_16x16x32_f16(ah, bh[s], q, 0, 0, 0);
      acc = __builtin_amdgcn_mfma_f32_16x16x32_f16(ah, bl[s], acc, 0, 0, 0);
      acc = __builtin_amdgcn_mfma_f32_16x16x32_f16(al, bh[s], acc, 0, 0, 0);
      int jbase = jt * 16 + grp * 4;
      acc.x = (jbase + 0 == rS[s]) ? -3.4e38f : acc.x;
      acc.y = (jbase + 1 == rS[s]) ? -3.4e38f : acc.y;
      acc.z = (jbase + 2 == rS[s]) ? -3.4e38f : acc.z;
      acc.w = (jbase + 3 == rS[s]) ? -3.4e38f : acc.w;
      float m = fmaxf(fmaxf(acc.x, acc.y), fmaxf(acc.z, acc.w));
      if (__ballot(m >= tS[s])) {
        float av[4] = {acc.x, acc.y, acc.z, acc.w};
        #pragma unroll
        for (int e = 0; e < 4; ++e) {
          if (av[e] >= tS[s]) {
            unsigned sl = atomicAdd(gcnt + rS[s], 1u);
            if (sl < (unsigned)NS) gbuf[(size_t)rS[s] * NS + sl] = pack_key(av[e], jbase + e);
          }
        }
      }
    }
  }
}

// ---- h = x @ gat_w + logits. LDS-FREE: gw column in regs, x row via uniform loads. ----
__global__ __launch_bounds__(256) void k_feat(
    const float* __restrict__ x, const float* __restrict__ gw,
    const float* __restrict__ aw_s, const float* __restrict__ aw_d,
    float* __restrict__ h, float* __restrict__ asrc, float* __restrict__ adst)
{
  const int tid = threadIdx.x;
  const int d = tid & 127, half = tid >> 7;      // wave-uniform half (waves 0,1 / 2,3)
  const int head = d >> 5, hid = d & 31;

  float gwr[32];
  #pragma unroll
  for (int k = 0; k < 32; ++k) gwr[k] = gw[k * 128 + d];   // coalesced across d
  const float ws_ = aw_s[head * 32 + hid], wd_ = aw_d[head * 32 + hid];

  #pragma unroll
  for (int p = 0; p < 8; ++p) {
    int nl = (p << 1) | half;                    // wave-uniform node
    int n = blockIdx.x * 16 + nl;
    const float4* xr = (const float4*)(x + (size_t)n * 32);  // uniform address
    float acc = 0.f;
    #pragma unroll
    for (int r = 0; r < 8; ++r) {
      float4 v = xr[r];
      acc = fmaf(v.x, gwr[r * 4 + 0], acc);
      acc = fmaf(v.y, gwr[r * 4 + 1], acc);
      acc = fmaf(v.z, gwr[r * 4 + 2], acc);
      acc = fmaf(v.w, gwr[r * 4 + 3], acc);
    }
    h[(size_t)n * 128 + d] = acc;
    float ps = acc * ws_, pd = acc * wd_;
    #pragma unroll
    for (int off = 16; off; off >>= 1) {
      ps += __shfl_xor(ps, off, 32);
      pd += __shfl_xor(pd, off, 32);
    }
    if (hid == 0) { asrc[n * 4 + head] = ps; adst[n * 4 + head] = pd; }
  }
}

// -------- GAT + ELU + partial batch mean (16 nodes/block, 4 partials per batch) --------
__global__ __launch_bounds__(256) void k_gat(
    const float* __restrict__ h, const float* __restrict__ asrc, const float* __restrict__ adst,
    const unsigned long long* __restrict__ gbuf, const float* __restrict__ gb,
    float* __restrict__ mo_part)
{
  int b2 = blockIdx.x;                 // 1024 blocks: batch b = b2>>2, quarter qq = b2&3
  int b = b2 >> 2, qq = b2 & 3;
  int tid = threadIdx.x;
  __shared__ int4 sknn[16];
  if (tid < 16) {
    int row = b * 64 + qq * 16 + tid;
    unsigned long long K0 = ~0ull, K1 = ~0ull, K2 = ~0ull, K3 = ~0ull;
    const unsigned long long* src = gbuf + (size_t)row * NS;
    #pragma unroll
    for (int e = 0; e < NS; ++e) {
      unsigned long long cc = src[e];
      bool g = cc < K3, c0 = cc < K0, c1 = cc < K1, c2 = cc < K2;
      unsigned long long n1 = c0 ? K0 : (c1 ? cc : K1);
      unsigned long long n2 = c1 ? K1 : (c2 ? cc : K2);
      unsigned long long n3 = c2 ? K2 : (g ? cc : K3);
      K0 = c0 ? cc : K0; K1 = n1; K2 = n2; K3 = n3;
    }
    sknn[tid] = make_int4((int)(unsigned)K0, (int)(unsigned)K1,
                          (int)(unsigned)K2, (int)(unsigned)K3);
  }
  __syncthreads();

  int w = tid >> 6, lane = tid & 63;
  int da = lane, db = lane + 64;
  int ha = lane >> 5, hb = ha + 2;
  float acca = 0.f, accb = 0.f;

  #pragma unroll
  for (int t = 0; t < 4; ++t) {
    int nl = t * 4 + w;
    int n = b * 64 + qq * 16 + nl;
    int4 nb = sknn[nl];
    int nbs[5] = {nb.x, nb.y, nb.z, nb.w, n};
    float ad_a = adst[n * 4 + ha], ad_b = adst[n * 4 + hb];
    float ea[5], eb[5];
    #pragma unroll
    for (int k = 0; k < 5; ++k) {
      float va = ad_a + asrc[nbs[k] * 4 + ha];
      float vb = ad_b + asrc[nbs[k] * 4 + hb];
      ea[k] = va > 0.f ? va : 0.2f * va;
      eb[k] = vb > 0.f ? vb : 0.2f * vb;
    }
    float ma = ea[0], mb = eb[0];
    #pragma unroll
    for (int k = 1; k < 5; ++k) { ma = fmaxf(ma, ea[k]); mb = fmaxf(mb, eb[k]); }
    float sa = 0.f, sb = 0.f;
    #pragma unroll
    for (int k = 0; k < 5; ++k) {
      ea[k] = __expf(ea[k] - ma); sa += ea[k];
      eb[k] = __expf(eb[k] - mb); sb += eb[k];
    }
    float outa = 0.f, outb = 0.f;
    #pragma unroll
    for (int k = 0; k < 5; ++k) {
      const float* hr = h + (size_t)nbs[k] * 128;
      outa = fmaf(ea[k], hr[da], outa);
      outb = fmaf(eb[k], hr[db], outb);
    }
    outa = outa / sa + gb[da];
    outb = outb / sb + gb[db];
    acca += outa > 0.f ? outa : expm1f(outa);
    accb += outb > 0.f ? outb : expm1f(outb);
  }

  __shared__ float red[4][128];
  red[w][da] = acca; red[w][db] = accb;
  __syncthreads();
  if (tid < 128) {
    float s = (red[0][tid] + red[1][tid] + red[2][tid] + red[3][tid]) * (1.f / 64.f);
    mo_part[b2 * 128 + tid] = s;
  }
}

// ---------------- final FC 128 -> 2 (sums the 4 mean partials) ----------------
__global__ __launch_bounds__(64) void k_fc(
    const float* __restrict__ mo_part, const float* __restrict__ fw, const float* __restrict__ fb,
    float* __restrict__ out)
{
  int b = blockIdx.x, lane = threadIdx.x;
  float m0 = 0.f, m1 = 0.f;
  #pragma unroll
  for (int q = 0; q < 4; ++q) {
    m0 += mo_part[(b * 4 + q) * 128 + lane];
    m1 += mo_part[(b * 4 + q) * 128 + lane + 64];
  }
  float p0 = m0 * fw[lane * 2]     + m1 * fw[(lane + 64) * 2];
  float p1 = m0 * fw[lane * 2 + 1] + m1 * fw[(lane + 64) * 2 + 1];
  #pragma unroll
  for (int off = 32; off; off >>= 1) {
    p0 += __shfl_xor(p0, off, 64);
    p1 += __shfl_xor(p1, off, 64);
  }
  if (lane == 0) { out[b * 2] = p0 + fb[0]; out[b * 2 + 1] = p1 + fb[1]; }
}

extern "C" void kernel_launch(void* const* d_in, const int* in_sizes, int n_in,
                              void* d_out, int out_size, void* d_ws, size_t ws_size,
                              hipStream_t stream)
{
  const float* x   = (const float*)d_in[0];
  // d_in[1..4] = edge-MLP weights: dead code in the reference output, skipped.
  const float* gw  = (const float*)d_in[5];
  const float* as_ = (const float*)d_in[6];
  const float* ad_ = (const float*)d_in[7];
  const float* gb  = (const float*)d_in[8];
  const float* fw  = (const float*)d_in[9];
  const float* fb  = (const float*)d_in[10];

  char* ws = (char*)d_ws;
  float*  cvals  = (float*)(ws);                         // 2 MB
  float*  h      = (float*)(ws + 2097152);               // 8 MB
  float*  asrc   = (float*)(ws + 10485760);              // 256 KB
  float*  adst   = (float*)(ws + 10747904);              // 256 KB
  float4* fragHi = (float4*)(ws + 11010048);             // 1 MB
  float4* fragLo = (float4*)(ws + 12058624);             // 1 MB
  float*  nsq    = (float*)(ws + 13107200);              // 64 KB
  float*  tau    = (float*)(ws + 13172736);              // 64 KB
  unsigned* gcnt = (unsigned*)(ws + 13238272);           // 64 KB
  unsigned long long* gbuf = (unsigned long long*)(ws + 13303808); // 2 MB
  unsigned* bcnt = (unsigned*)(ws + 15400960);           // 256 B
  float*  nmx    = (float*)(ws + 15401216);              // 256 B (2 floats used)
  int*    bucket = (int*)   (ws + 15401472);             // 2 MB
  float*  mo_part= (float*)(ws + 17498624);              // 512 KB
  float*  outp   = (float*)d_out;

  hipMemsetAsync(nmx, 0, 8, stream);   // norm maxes start at +0.0f
  k_prep<<<256, 64, 0, stream>>>(x, fragHi, fragLo, nsq, gcnt, gbuf, bcnt, nmx);
  k_knnA<<<dim3(64, NCHUNK), 256, 0, stream>>>(fragHi, nsq, cvals);
  k_tauwl<<<N_PTS / 64, 128, 0, stream>>>(cvals, tau, bcnt, bucket, nmx);
  k_knnBW<<<dim3(NCHUNK, 256 * JSPLIT), 256, 0, stream>>>(fragHi, fragLo, nsq, tau,
                                                          bcnt, bucket, gcnt, gbuf);
  k_feat<<<N_PTS / 16, 256, 0, stream>>>(x, gw, as_, ad_, h, asrc, adst);
  k_gat<<<1024, 256, 0, stream>>>(h, asrc, adst, gbuf, gb, mo_part);
  k_fc<<<256, 64, 0, stream>>>(mo_part, fw, fb, outp);
}

// Round 22
// 100.216 us; speedup vs baseline: 1.1699x; 1.0744x over previous
//
#include <hip/hip_runtime.h>
#include <math.h>

#define N_PTS   16384
#define NT      1024         // 16-point tiles
#define NCHUNK  32
#define JT_CH   (NT/NCHUNK)  // 32 j-tiles per chunk
#define SUBT    16           // tiles per LDS staging round (hi only: 17 KB)
#define NSUB    (JT_CH/SUBT) // 2
#define NS      16           // gbuf slots per row
#define JSPLIT  4            // pass-B j-segments per chunk
#define NPB     256          // k_prep blocks (pmax entries)

typedef __attribute__((ext_vector_type(4))) float f32x4;
typedef __attribute__((ext_vector_type(8))) _Float16 half8;

union H8 { half8 h; float4 f; };

#define MED3(a,b,c) __builtin_amdgcn_fmed3f((a),(b),(c))

// branch-free exact top-4 (desc) insert: 1 max + 3 med3, ALL INDEPENDENT (1 dep level)
#define INS4(c, A0, A1, A2, A3) {        \
  float n0_ = fmaxf(A0, c);              \
  float n1_ = MED3(A0, A1, c);           \
  float n2_ = MED3(A1, A2, c);           \
  float n3_ = MED3(A2, A3, c);           \
  A0 = n0_; A1 = n1_; A2 = n2_; A3 = n3_; }

__device__ __forceinline__ unsigned long long pack_key(float a, int j) {
  unsigned u = __float_as_uint(a);
  unsigned ord = u ^ (unsigned)(((int)u >> 31) | 0x80000000);
  unsigned m = ~ord;                      // ascending m <-> descending acc <-> ascending d
  return ((unsigned long long)m << 32) | (unsigned)j;
}

// ---------------- Kernel P: f16 hi/lo fragments + (-sq/2) + per-block norm maxes ------
__global__ __launch_bounds__(64) void k_prep(
    const float* __restrict__ x, float4* __restrict__ fragHi,
    float4* __restrict__ fragLo, float* __restrict__ nsq,
    unsigned* __restrict__ gcnt, unsigned long long* __restrict__ gbuf,
    unsigned* __restrict__ bcnt, float2* __restrict__ pmax)
{
  int p = blockIdx.x * 64 + threadIdx.x;
  const float4* xp = (const float4*)(x + (size_t)p * 32);
  int tile = p >> 4, lb = p & 15;
  float sq = 0.f, hn2 = 0.f, ln2 = 0.f;
  #pragma unroll
  for (int g = 0; g < 4; ++g) {
    float4 va = xp[g * 2], vb = xp[g * 2 + 1];
    float f[8] = {va.x, va.y, va.z, va.w, vb.x, vb.y, vb.z, vb.w};
    H8 hh, hl;
    #pragma unroll
    for (int e = 0; e < 8; ++e) {
      sq = fmaf(f[e], f[e], sq);
      _Float16 hi = (_Float16)f[e];
      _Float16 lo = (_Float16)(f[e] - (float)hi);
      hh.h[e] = hi; hl.h[e] = lo;
      float hf = (float)hi, lf = (float)lo;
      hn2 = fmaf(hf, hf, hn2);
      ln2 = fmaf(lf, lf, ln2);
    }
    int a = tile * 64 + g * 16 + lb;
    fragHi[a] = hh.f; fragLo[a] = hl.f;
  }
  nsq[p] = -0.5f * sq;
  gcnt[p] = 0u;
  #pragma unroll
  for (int e = 0; e < NS; ++e) gbuf[(size_t)p * NS + e] = ~0ull;
  if (blockIdx.x == 0 && threadIdx.x < NCHUNK) bcnt[threadIdx.x] = 0u;

  // wave-reduce block's squared-norm maxima; plain store (no init required)
  #pragma unroll
  for (int off = 32; off; off >>= 1) {
    hn2 = fmaxf(hn2, __shfl_xor(hn2, off));
    ln2 = fmaxf(ln2, __shfl_xor(ln2, off));
  }
  if (threadIdx.x == 0) pmax[blockIdx.x] = make_float2(hn2, ln2);
}

// ---- Pass A: per-(row,chunk) chunk-max of G = hi.hi + q  (SINGLE MFMA per tile-pair).
// G is bit-identical to the first partial of pass-B's F-chain; the |F-G| <= EPS bound
// is applied in k_tauwl, keeping the gate exact.
__global__ __launch_bounds__(256, 4) void k_knnA(
    const float4* __restrict__ fragHi, const float* __restrict__ nsq,
    float* __restrict__ cvals)
{
  __shared__ half8 sHi[SUBT * 64];     // 16 KB
  __shared__ float sNq[SUBT * 16];     // 1 KB

  const int tid = threadIdx.x;
  const int w = tid >> 6, lane = tid & 63;
  const int grp = lane >> 4, col = lane & 15;
  const int cy = blockIdx.y;
  const int itbase = blockIdx.x * 16 + w * 4;      // 4 i-tile strips per wave
  const bool blkdiag = ((int)(blockIdx.x >> 1) == cy);

  const half8* fH8 = (const half8*)fragHi;

  half8 bh[4];
  #pragma unroll
  for (int s = 0; s < 4; ++s)
    bh[s] = fH8[(size_t)(itbase + s) * 64 + lane];
  const bool dg0 = (col == grp * 4 + 0), dg1 = (col == grp * 4 + 1);
  const bool dg2 = (col == grp * 4 + 2), dg3 = (col == grp * 4 + 3);

  float La1[4];
  #pragma unroll
  for (int s = 0; s < 4; ++s) La1[s] = -3.4e38f;

  for (int sc = 0; sc < NSUB; ++sc) {
    int jt0 = cy * JT_CH + sc * SUBT;
    __syncthreads();
    const float4* gH = fragHi + (size_t)jt0 * 64;
    float4* dH = (float4*)sHi;
    #pragma unroll
    for (int r = 0; r < 4; ++r)
      dH[tid + r * 256] = gH[tid + r * 256];
    sNq[tid] = nsq[jt0 * 16 + tid];
    __syncthreads();

    for (int t = 0; t < SUBT; ++t) {
      half8 ah = sHi[t * 64 + lane];
      f32x4 q = *(const f32x4*)&sNq[t * 16 + grp * 4];
      int jt = jt0 + t;
      #pragma unroll
      for (int s = 0; s < 4; ++s) {
        f32x4 acc = __builtin_amdgcn_mfma_f32_16x16x32_f16(ah, bh[s], q, 0, 0, 0);
        if (blkdiag && jt == itbase + s) {         // diagonal tile: exclude j==i
          acc.x = dg0 ? -3.4e38f : acc.x;
          acc.y = dg1 ? -3.4e38f : acc.y;
          acc.z = dg2 ? -3.4e38f : acc.z;
          acc.w = dg3 ? -3.4e38f : acc.w;
        }
        float t3 = fmaxf(fmaxf(acc.x, acc.y), acc.z);   // v_max3
        La1[s] = fmaxf(fmaxf(t3, acc.w), La1[s]);       // v_max3
      }
    }
  }

  #pragma unroll
  for (int s = 0; s < 4; ++s) {
    float m = La1[s];
    m = fmaxf(m, __shfl_xor(m, 16));
    m = fmaxf(m, __shfl_xor(m, 32));
    if (grp == 0) {
      int row = (itbase + s) * 16 + col;
      cvals[(size_t)cy * N_PTS + row] = m;     // chunk-major, coalesced
    }
  }
}

// ---- tau' + worklist: theta = (4th-largest G-chunk-max) - 2*EPS; bucket cmax >= theta ----
__global__ __launch_bounds__(128) void k_tauwl(
    const float* __restrict__ cvals, float* __restrict__ tau,
    unsigned* __restrict__ bcnt, int* __restrict__ bucket,
    const float2* __restrict__ pmax)
{
  __shared__ unsigned lcnt[NCHUNK];
  __shared__ unsigned gbase[NCHUNK];
  __shared__ int stage[NCHUNK][64];
  __shared__ float4 sL[64];
  __shared__ float sT[64];
  __shared__ float sEps;

  const int tid = threadIdx.x;
  const int lrow = tid & 63, half = tid >> 6;
  const int row = blockIdx.x * 64 + lrow;
  if (tid < NCHUNK) lcnt[tid] = 0u;

  // reduce 256 per-block norm maxima -> eps (wave 0 only; L2-hot)
  if (tid < 64) {
    float hm = 0.f, lm = 0.f;
    #pragma unroll
    for (int k = 0; k < NPB / 64; ++k) {
      float2 v = pmax[tid + k * 64];
      hm = fmaxf(hm, v.x);
      lm = fmaxf(lm, v.y);
    }
    #pragma unroll
    for (int off = 32; off; off >>= 1) {
      hm = fmaxf(hm, __shfl_xor(hm, off));
      lm = fmaxf(lm, __shfl_xor(lm, off));
    }
    // 2*EPS with 1.1x safety + absolute slack for fp32 accumulation differences
    if (tid == 0) sEps = 4.4f * sqrtf(hm) * sqrtf(lm) + 1e-3f;
  }
  __syncthreads();
  const float eps = sEps;

  float A0 = -3.4e38f, A1 = -3.4e38f, A2 = -3.4e38f, A3 = -3.4e38f;
  float cm[16];
  #pragma unroll
  for (int k = 0; k < 16; ++k) {
    cm[k] = cvals[(size_t)(half * 16 + k) * N_PTS + row];  // coalesced
    INS4(cm[k], A0, A1, A2, A3);
  }
  if (half == 1) sL[lrow] = make_float4(A0, A1, A2, A3);
  __syncthreads();
  if (half == 0) {
    float4 o = sL[lrow];
    INS4(o.x, A0, A1, A2, A3);
    INS4(o.y, A0, A1, A2, A3);
    INS4(o.z, A0, A1, A2, A3);
    INS4(o.w, A0, A1, A2, A3);
    float theta = A3 - eps;
    sT[lrow] = theta;
    tau[row] = theta;
  }
  __syncthreads();
  const float tt = sT[lrow];
  #pragma unroll
  for (int k = 0; k < 16; ++k) {
    if (cm[k] >= tt) {                          // chunk may hold a global top-4 member
      int c = half * 16 + k;
      unsigned p = atomicAdd(&lcnt[c], 1u);     // LDS atomic
      stage[c][p] = row;
    }
  }
  __syncthreads();
  if (tid < NCHUNK) gbase[tid] = atomicAdd(bcnt + tid, lcnt[tid]);
  __syncthreads();
  for (int c = 0; c < NCHUNK; ++c) {
    unsigned n = lcnt[c], gb = gbase[c];
    for (unsigned k = tid; k < n; k += 128)
      bucket[c * N_PTS + gb + k] = stage[c][k];
  }
}

// ---- Pass B (worklist): full F (3 MFMA), j-split 4-ways; emits F >= theta (exact) ----
__global__ __launch_bounds__(256) void k_knnBW(
    const float4* __restrict__ fragHi, const float4* __restrict__ fragLo,
    const float* __restrict__ nsq, const float* __restrict__ tau,
    const unsigned* __restrict__ bcnt, const int* __restrict__ bucket,
    unsigned* __restrict__ gcnt, unsigned long long* __restrict__ gbuf)
{
  const int c = blockIdx.x;
  const int jseg = blockIdx.y >> 8;
  const unsigned n = bcnt[c];
  const unsigned base = (unsigned)(blockIdx.y & 255) * 64;
  if (base >= n) return;

  __shared__ int   sRow[64];
  __shared__ float sTau[64];

  const int tid = threadIdx.x;
  const int w = tid >> 6, lane = tid & 63;
  const int grp = lane >> 4, col = lane & 15;
  const float INF = __int_as_float(0x7f800000);

  if (tid < 64) {
    unsigned idx = base + tid;
    int myrow = (idx < n) ? bucket[c * N_PTS + idx] : -1;
    sRow[tid] = myrow;
    sTau[tid] = (myrow >= 0) ? tau[myrow] : INF;
  }
  __syncthreads();

  const half8* fH8 = (const half8*)fragHi;
  const half8* fL8 = (const half8*)fragLo;

  half8 bh[4], bl[4];
  int   rS[4];
  float tS[4];
  #pragma unroll
  for (int s = 0; s < 4; ++s) {
    int r = sRow[s * 16 + col];
    rS[s] = r;
    tS[s] = sTau[s * 16 + col];
    int rr = r < 0 ? 0 : r;
    size_t a = (size_t)(rr >> 4) * 64 + grp * 16 + (rr & 15);
    bh[s] = fH8[a];
    bl[s] = fL8[a];
  }

  // wave w handles j-tiles jt0..jt0+1 (2 serial iterations)
  const int jt0 = c * JT_CH + jseg * (JT_CH / JSPLIT) + w * (JT_CH / (JSPLIT * 4));
  #pragma unroll
  for (int ti = 0; ti < JT_CH / (JSPLIT * 4); ++ti) {
    int jt = jt0 + ti;
    half8 ah = fH8[(size_t)jt * 64 + lane];
    half8 al = fL8[(size_t)jt * 64 + lane];
    f32x4 q = *(const f32x4*)&nsq[jt * 16 + grp * 4];
    #pragma unroll
    for (int s = 0; s < 4; ++s) {
      f32x4 acc = __builtin_amdgcn_mfma_f32_16x16x32_f16(ah, bh[s], q, 0, 0, 0);
      acc = __builtin_amdgcn_mfma_f32_16x16x32_f16(ah, bl[s], acc, 0, 0, 0);
      acc = __builtin_amdgcn_mfma_f32_16x16x32_f16(al, bh[s], acc, 0, 0, 0);
      int jbase = jt * 16 + grp * 4;
      acc.x = (jbase + 0 == rS[s]) ? -3.4e38f : acc.x;
      acc.y = (jbase + 1 == rS[s]) ? -3.4e38f : acc.y;
      acc.z = (jbase + 2 == rS[s]) ? -3.4e38f : acc.z;
      acc.w = (jbase + 3 == rS[s]) ? -3.4e38f : acc.w;
      float m = fmaxf(fmaxf(acc.x, acc.y), fmaxf(acc.z, acc.w));
      if (__ballot(m >= tS[s])) {
        float av[4] = {acc.x, acc.y, acc.z, acc.w};
        #pragma unroll
        for (int e = 0; e < 4; ++e) {
          if (av[e] >= tS[s]) {
            unsigned sl = atomicAdd(gcnt + rS[s], 1u);
            if (sl < (unsigned)NS) gbuf[(size_t)rS[s] * NS + sl] = pack_key(av[e], jbase + e);
          }
        }
      }
    }
  }
}

// ---- h = x @ gat_w + logits. LDS-FREE: gw column in regs, x row via uniform loads. ----
__global__ __launch_bounds__(256) void k_feat(
    const float* __restrict__ x, const float* __restrict__ gw,
    const float* __restrict__ aw_s, const float* __restrict__ aw_d,
    float* __restrict__ h, float* __restrict__ asrc, float* __restrict__ adst)
{
  const int tid = threadIdx.x;
  const int d = tid & 127, half = tid >> 7;      // wave-uniform half (waves 0,1 / 2,3)
  const int head = d >> 5, hid = d & 31;

  float gwr[32];
  #pragma unroll
  for (int k = 0; k < 32; ++k) gwr[k] = gw[k * 128 + d];   // coalesced across d
  const float ws_ = aw_s[head * 32 + hid], wd_ = aw_d[head * 32 + hid];

  #pragma unroll
  for (int p = 0; p < 8; ++p) {
    int nl = (p << 1) | half;                    // wave-uniform node
    int n = blockIdx.x * 16 + nl;
    const float4* xr = (const float4*)(x + (size_t)n * 32);  // uniform address
    float acc = 0.f;
    #pragma unroll
    for (int r = 0; r < 8; ++r) {
      float4 v = xr[r];
      acc = fmaf(v.x, gwr[r * 4 + 0], acc);
      acc = fmaf(v.y, gwr[r * 4 + 1], acc);
      acc = fmaf(v.z, gwr[r * 4 + 2], acc);
      acc = fmaf(v.w, gwr[r * 4 + 3], acc);
    }
    h[(size_t)n * 128 + d] = acc;
    float ps = acc * ws_, pd = acc * wd_;
    #pragma unroll
    for (int off = 16; off; off >>= 1) {
      ps += __shfl_xor(ps, off, 32);
      pd += __shfl_xor(pd, off, 32);
    }
    if (hid == 0) { asrc[n * 4 + head] = ps; adst[n * 4 + head] = pd; }
  }
}

// -------- GAT + ELU + partial batch mean (16 nodes/block, 4 partials per batch) --------
__global__ __launch_bounds__(256) void k_gat(
    const float* __restrict__ h, const float* __restrict__ asrc, const float* __restrict__ adst,
    const unsigned long long* __restrict__ gbuf, const float* __restrict__ gb,
    float* __restrict__ mo_part)
{
  int b2 = blockIdx.x;                 // 1024 blocks: batch b = b2>>2, quarter qq = b2&3
  int b = b2 >> 2, qq = b2 & 3;
  int tid = threadIdx.x;
  __shared__ int4 sknn[16];
  if (tid < 16) {
    int row = b * 64 + qq * 16 + tid;
    unsigned long long K0 = ~0ull, K1 = ~0ull, K2 = ~0ull, K3 = ~0ull;
    const unsigned long long* src = gbuf + (size_t)row * NS;
    #pragma unroll
    for (int e = 0; e < NS; ++e) {
      unsigned long long cc = src[e];
      bool g = cc < K3, c0 = cc < K0, c1 = cc < K1, c2 = cc < K2;
      unsigned long long n1 = c0 ? K0 : (c1 ? cc : K1);
      unsigned long long n2 = c1 ? K1 : (c2 ? cc : K2);
      unsigned long long n3 = c2 ? K2 : (g ? cc : K3);
      K0 = c0 ? cc : K0; K1 = n1; K2 = n2; K3 = n3;
    }
    sknn[tid] = make_int4((int)(unsigned)K0, (int)(unsigned)K1,
                          (int)(unsigned)K2, (int)(unsigned)K3);
  }
  __syncthreads();

  int w = tid >> 6, lane = tid & 63;
  int da = lane, db = lane + 64;
  int ha = lane >> 5, hb = ha + 2;
  float acca = 0.f, accb = 0.f;

  #pragma unroll
  for (int t = 0; t < 4; ++t) {
    int nl = t * 4 + w;
    int n = b * 64 + qq * 16 + nl;
    int4 nb = sknn[nl];
    int nbs[5] = {nb.x, nb.y, nb.z, nb.w, n};
    float ad_a = adst[n * 4 + ha], ad_b = adst[n * 4 + hb];
    float ea[5], eb[5];
    #pragma unroll
    for (int k = 0; k < 5; ++k) {
      float va = ad_a + asrc[nbs[k] * 4 + ha];
      float vb = ad_b + asrc[nbs[k] * 4 + hb];
      ea[k] = va > 0.f ? va : 0.2f * va;
      eb[k] = vb > 0.f ? vb : 0.2f * vb;
    }
    float ma = ea[0], mb = eb[0];
    #pragma unroll
    for (int k = 1; k < 5; ++k) { ma = fmaxf(ma, ea[k]); mb = fmaxf(mb, eb[k]); }
    float sa = 0.f, sb = 0.f;
    #pragma unroll
    for (int k = 0; k < 5; ++k) {
      ea[k] = __expf(ea[k] - ma); sa += ea[k];
      eb[k] = __expf(eb[k] - mb); sb += eb[k];
    }
    float outa = 0.f, outb = 0.f;
    #pragma unroll
    for (int k = 0; k < 5; ++k) {
      const float* hr = h + (size_t)nbs[k] * 128;
      outa = fmaf(ea[k], hr[da], outa);
      outb = fmaf(eb[k], hr[db], outb);
    }
    outa = outa / sa + gb[da];
    outb = outb / sb + gb[db];
    acca += outa > 0.f ? outa : expm1f(outa);
    accb += outb > 0.f ? outb : expm1f(outb);
  }

  __shared__ float red[4][128];
  red[w][da] = acca; red[w][db] = accb;
  __syncthreads();
  if (tid < 128) {
    float s = (red[0][tid] + red[1][tid] + red[2][tid] + red[3][tid]) * (1.f / 64.f);
    mo_part[b2 * 128 + tid] = s;
  }
}

// ---------------- final FC 128 -> 2 (sums the 4 mean partials) ----------------
__global__ __launch_bounds__(64) void k_fc(
    const float* __restrict__ mo_part, const float* __restrict__ fw, const float* __restrict__ fb,
    float* __restrict__ out)
{
  int b = blockIdx.x, lane = threadIdx.x;
  float m0 = 0.f, m1 = 0.f;
  #pragma unroll
  for (int q = 0; q < 4; ++q) {
    m0 += mo_part[(b * 4 + q) * 128 + lane];
    m1 += mo_part[(b * 4 + q) * 128 + lane + 64];
  }
  float p0 = m0 * fw[lane * 2]     + m1 * fw[(lane + 64) * 2];
  float p1 = m0 * fw[lane * 2 + 1] + m1 * fw[(lane + 64) * 2 + 1];
  #pragma unroll
  for (int off = 32; off; off >>= 1) {
    p0 += __shfl_xor(p0, off, 64);
    p1 += __shfl_xor(p1, off, 64);
  }
  if (lane == 0) { out[b * 2] = p0 + fb[0]; out[b * 2 + 1] = p1 + fb[1]; }
}

extern "C" void kernel_launch(void* const* d_in, const int* in_sizes, int n_in,
                              void* d_out, int out_size, void* d_ws, size_t ws_size,
                              hipStream_t stream)
{
  const float* x   = (const float*)d_in[0];
  // d_in[1..4] = edge-MLP weights: dead code in the reference output, skipped.
  const float* gw  = (const float*)d_in[5];
  const float* as_ = (const float*)d_in[6];
  const float* ad_ = (const float*)d_in[7];
  const float* gb  = (const float*)d_in[8];
  const float* fw  = (const float*)d_in[9];
  const float* fb  = (const float*)d_in[10];

  char* ws = (char*)d_ws;
  float*  cvals  = (float*)(ws);                         // 2 MB
  float*  h      = (float*)(ws + 2097152);               // 8 MB
  float*  asrc   = (float*)(ws + 10485760);              // 256 KB
  float*  adst   = (float*)(ws + 10747904);              // 256 KB
  float4* fragHi = (float4*)(ws + 11010048);             // 1 MB
  float4* fragLo = (float4*)(ws + 12058624);             // 1 MB
  float*  nsq    = (float*)(ws + 13107200);              // 64 KB
  float*  tau    = (float*)(ws + 13172736);              // 64 KB
  unsigned* gcnt = (unsigned*)(ws + 13238272);           // 64 KB
  unsigned long long* gbuf = (unsigned long long*)(ws + 13303808); // 2 MB
  unsigned* bcnt = (unsigned*)(ws + 15400960);           // 256 B
  float2* pmax   = (float2*)(ws + 15401216);             // 2 KB (256 float2)
  int*    bucket = (int*)   (ws + 15403264);             // 2 MB
  float*  mo_part= (float*)(ws + 17500416);              // 512 KB
  float*  outp   = (float*)d_out;

  k_prep<<<NPB, 64, 0, stream>>>(x, fragHi, fragLo, nsq, gcnt, gbuf, bcnt, pmax);
  k_knnA<<<dim3(64, NCHUNK), 256, 0, stream>>>(fragHi, nsq, cvals);
  k_tauwl<<<N_PTS / 64, 128, 0, stream>>>(cvals, tau, bcnt, bucket, pmax);
  k_knnBW<<<dim3(NCHUNK, 256 * JSPLIT), 256, 0, stream>>>(fragHi, fragLo, nsq, tau,
                                                          bcnt, bucket, gcnt, gbuf);
  k_feat<<<N_PTS / 16, 256, 0, stream>>>(x, gw, as_, ad_, h, asrc, adst);
  k_gat<<<1024, 256, 0, stream>>>(h, asrc, adst, gbuf, gb, mo_part);
  k_fc<<<256, 64, 0, stream>>>(mo_part, fw, fb, outp);
}

// Round 23
// 94.193 us; speedup vs baseline: 1.2447x; 1.0639x over previous
//
#include <hip/hip_runtime.h>
#include <math.h>

#define N_PTS   16384
#define NT      1024         // 16-point tiles
#define NCHUNK  32
#define JT_CH   (NT/NCHUNK)  // 32 j-tiles per chunk
#define SUBT    16           // tiles per LDS staging round (hi only: 17 KB)
#define NSUB    (JT_CH/SUBT) // 2
#define NS      16           // gbuf slots per row
#define JSPLIT  4            // pass-B j-segments per chunk
#define NPB     256          // k_prep blocks (pmax entries)

typedef __attribute__((ext_vector_type(4))) float f32x4;
typedef __attribute__((ext_vector_type(8))) _Float16 half8;

union H8 { half8 h; float4 f; };

#define MED3(a,b,c) __builtin_amdgcn_fmed3f((a),(b),(c))

// branch-free exact top-4 (desc) insert: 1 max + 3 med3, ALL INDEPENDENT (1 dep level)
#define INS4(c, A0, A1, A2, A3) {        \
  float n0_ = fmaxf(A0, c);              \
  float n1_ = MED3(A0, A1, c);           \
  float n2_ = MED3(A1, A2, c);           \
  float n3_ = MED3(A2, A3, c);           \
  A0 = n0_; A1 = n1_; A2 = n2_; A3 = n3_; }

__device__ __forceinline__ unsigned long long pack_key(float a, int j) {
  unsigned u = __float_as_uint(a);
  unsigned ord = u ^ (unsigned)(((int)u >> 31) | 0x80000000);
  unsigned m = ~ord;                      // ascending m <-> descending acc <-> ascending d
  return ((unsigned long long)m << 32) | (unsigned)j;
}

// ---------------- Kernel P: f16 hi/lo fragments + (-sq/2) + per-block norm maxes ------
__global__ __launch_bounds__(64) void k_prep(
    const float* __restrict__ x, float4* __restrict__ fragHi,
    float4* __restrict__ fragLo, float* __restrict__ nsq,
    unsigned* __restrict__ gcnt, unsigned long long* __restrict__ gbuf,
    unsigned* __restrict__ bcnt, float2* __restrict__ pmax)
{
  int p = blockIdx.x * 64 + threadIdx.x;
  const float4* xp = (const float4*)(x + (size_t)p * 32);
  int tile = p >> 4, lb = p & 15;
  float sq = 0.f, hn2 = 0.f, ln2 = 0.f;
  #pragma unroll
  for (int g = 0; g < 4; ++g) {
    float4 va = xp[g * 2], vb = xp[g * 2 + 1];
    float f[8] = {va.x, va.y, va.z, va.w, vb.x, vb.y, vb.z, vb.w};
    H8 hh, hl;
    #pragma unroll
    for (int e = 0; e < 8; ++e) {
      sq = fmaf(f[e], f[e], sq);
      _Float16 hi = (_Float16)f[e];
      _Float16 lo = (_Float16)(f[e] - (float)hi);
      hh.h[e] = hi; hl.h[e] = lo;
      float hf = (float)hi, lf = (float)lo;
      hn2 = fmaf(hf, hf, hn2);
      ln2 = fmaf(lf, lf, ln2);
    }
    int a = tile * 64 + g * 16 + lb;
    fragHi[a] = hh.f; fragLo[a] = hl.f;
  }
  nsq[p] = -0.5f * sq;
  gcnt[p] = 0u;
  #pragma unroll
  for (int e = 0; e < NS; ++e) gbuf[(size_t)p * NS + e] = ~0ull;
  if (blockIdx.x == 0 && threadIdx.x < NCHUNK) bcnt[threadIdx.x] = 0u;

  // wave-reduce block's squared-norm maxima; plain store (no init required)
  #pragma unroll
  for (int off = 32; off; off >>= 1) {
    hn2 = fmaxf(hn2, __shfl_xor(hn2, off));
    ln2 = fmaxf(ln2, __shfl_xor(ln2, off));
  }
  if (threadIdx.x == 0) pmax[blockIdx.x] = make_float2(hn2, ln2);
}

// ---- FUSED Pass A + feat: cy < NCHUNK -> chunk-max of G = hi.hi + q (1 MFMA/tile-pair);
//      cy >= NCHUNK -> independent h = x@gat_w + logits (fills CUs as knnA retires). ----
__global__ __launch_bounds__(256, 4) void k_knnA(
    const float4* __restrict__ fragHi, const float* __restrict__ nsq,
    float* __restrict__ cvals,
    const float* __restrict__ x, const float* __restrict__ gw,
    const float* __restrict__ aw_s, const float* __restrict__ aw_d,
    float* __restrict__ h, float* __restrict__ asrc, float* __restrict__ adst)
{
  __shared__ half8 sHi[SUBT * 64];     // 16 KB
  __shared__ float sNq[SUBT * 16];     // 1 KB

  const int tid = threadIdx.x;
  const int cy = blockIdx.y;

  if (cy >= NCHUNK) {
    // ---------------- feat body (LDS-free, 16 nodes per block) ----------------
    const int fb = (cy - NCHUNK) * 64 + blockIdx.x;   // 0..1023
    const int d = tid & 127, half = tid >> 7;
    const int head = d >> 5, hid = d & 31;

    float gwr[32];
    #pragma unroll
    for (int k = 0; k < 32; ++k) gwr[k] = gw[k * 128 + d];
    const float ws_ = aw_s[head * 32 + hid], wd_ = aw_d[head * 32 + hid];

    #pragma unroll
    for (int p = 0; p < 8; ++p) {
      int nl = (p << 1) | half;
      int n = fb * 16 + nl;
      const float4* xr = (const float4*)(x + (size_t)n * 32);
      float acc = 0.f;
      #pragma unroll
      for (int r = 0; r < 8; ++r) {
        float4 v = xr[r];
        acc = fmaf(v.x, gwr[r * 4 + 0], acc);
        acc = fmaf(v.y, gwr[r * 4 + 1], acc);
        acc = fmaf(v.z, gwr[r * 4 + 2], acc);
        acc = fmaf(v.w, gwr[r * 4 + 3], acc);
      }
      h[(size_t)n * 128 + d] = acc;
      float ps = acc * ws_, pd = acc * wd_;
      #pragma unroll
      for (int off = 16; off; off >>= 1) {
        ps += __shfl_xor(ps, off, 32);
        pd += __shfl_xor(pd, off, 32);
      }
      if (hid == 0) { asrc[n * 4 + head] = ps; adst[n * 4 + head] = pd; }
    }
    return;
  }

  // ---------------- pass-A body ----------------
  const int w = tid >> 6, lane = tid & 63;
  const int grp = lane >> 4, col = lane & 15;
  const int itbase = blockIdx.x * 16 + w * 4;      // 4 i-tile strips per wave
  const bool blkdiag = ((int)(blockIdx.x >> 1) == cy);

  const half8* fH8 = (const half8*)fragHi;

  half8 bh[4];
  #pragma unroll
  for (int s = 0; s < 4; ++s)
    bh[s] = fH8[(size_t)(itbase + s) * 64 + lane];
  const bool dg0 = (col == grp * 4 + 0), dg1 = (col == grp * 4 + 1);
  const bool dg2 = (col == grp * 4 + 2), dg3 = (col == grp * 4 + 3);

  float La1[4];
  #pragma unroll
  for (int s = 0; s < 4; ++s) La1[s] = -3.4e38f;

  for (int sc = 0; sc < NSUB; ++sc) {
    int jt0 = cy * JT_CH + sc * SUBT;
    __syncthreads();
    const float4* gH = fragHi + (size_t)jt0 * 64;
    float4* dH = (float4*)sHi;
    #pragma unroll
    for (int r = 0; r < 4; ++r)
      dH[tid + r * 256] = gH[tid + r * 256];
    sNq[tid] = nsq[jt0 * 16 + tid];
    __syncthreads();

    for (int t = 0; t < SUBT; ++t) {
      half8 ah = sHi[t * 64 + lane];
      f32x4 q = *(const f32x4*)&sNq[t * 16 + grp * 4];
      int jt = jt0 + t;
      #pragma unroll
      for (int s = 0; s < 4; ++s) {
        f32x4 acc = __builtin_amdgcn_mfma_f32_16x16x32_f16(ah, bh[s], q, 0, 0, 0);
        if (blkdiag && jt == itbase + s) {         // diagonal tile: exclude j==i
          acc.x = dg0 ? -3.4e38f : acc.x;
          acc.y = dg1 ? -3.4e38f : acc.y;
          acc.z = dg2 ? -3.4e38f : acc.z;
          acc.w = dg3 ? -3.4e38f : acc.w;
        }
        float t3 = fmaxf(fmaxf(acc.x, acc.y), acc.z);   // v_max3
        La1[s] = fmaxf(fmaxf(t3, acc.w), La1[s]);       // v_max3
      }
    }
  }

  #pragma unroll
  for (int s = 0; s < 4; ++s) {
    float m = La1[s];
    m = fmaxf(m, __shfl_xor(m, 16));
    m = fmaxf(m, __shfl_xor(m, 32));
    if (grp == 0) {
      int row = (itbase + s) * 16 + col;
      cvals[(size_t)cy * N_PTS + row] = m;     // chunk-major, coalesced
    }
  }
}

// ---- tau' + worklist: theta = (4th-largest G-chunk-max) - 2.2*Mh*Ml; bucket >= theta ----
__global__ __launch_bounds__(128) void k_tauwl(
    const float* __restrict__ cvals, float* __restrict__ tau,
    unsigned* __restrict__ bcnt, int* __restrict__ bucket,
    const float2* __restrict__ pmax)
{
  __shared__ unsigned lcnt[NCHUNK];
  __shared__ unsigned gbase[NCHUNK];
  __shared__ int stage[NCHUNK][64];
  __shared__ float4 sL[64];
  __shared__ float sT[64];
  __shared__ float sEps;

  const int tid = threadIdx.x;
  const int lrow = tid & 63, half = tid >> 6;
  const int row = blockIdx.x * 64 + lrow;
  if (tid < NCHUNK) lcnt[tid] = 0u;

  // reduce 256 per-block norm maxima -> eps (wave 0 only; L2-hot)
  if (tid < 64) {
    float hm = 0.f, lm = 0.f;
    #pragma unroll
    for (int k = 0; k < NPB / 64; ++k) {
      float2 v = pmax[tid + k * 64];
      hm = fmaxf(hm, v.x);
      lm = fmaxf(lm, v.y);
    }
    #pragma unroll
    for (int off = 32; off; off >>= 1) {
      hm = fmaxf(hm, __shfl_xor(hm, off));
      lm = fmaxf(lm, __shfl_xor(lm, off));
    }
    // 2*EPS with 1.1x safety + absolute slack for fp32 accumulation differences
    if (tid == 0) sEps = 4.4f * sqrtf(hm) * sqrtf(lm) + 1e-3f;
  }
  __syncthreads();
  const float eps = sEps;

  float A0 = -3.4e38f, A1 = -3.4e38f, A2 = -3.4e38f, A3 = -3.4e38f;
  float cm[16];
  #pragma unroll
  for (int k = 0; k < 16; ++k) {
    cm[k] = cvals[(size_t)(half * 16 + k) * N_PTS + row];  // coalesced
    INS4(cm[k], A0, A1, A2, A3);
  }
  if (half == 1) sL[lrow] = make_float4(A0, A1, A2, A3);
  __syncthreads();
  if (half == 0) {
    float4 o = sL[lrow];
    INS4(o.x, A0, A1, A2, A3);
    INS4(o.y, A0, A1, A2, A3);
    INS4(o.z, A0, A1, A2, A3);
    INS4(o.w, A0, A1, A2, A3);
    float theta = A3 - eps;
    sT[lrow] = theta;
    tau[row] = theta;
  }
  __syncthreads();
  const float tt = sT[lrow];
  #pragma unroll
  for (int k = 0; k < 16; ++k) {
    if (cm[k] >= tt) {                          // chunk may hold a global top-4 member
      int c = half * 16 + k;
      unsigned p = atomicAdd(&lcnt[c], 1u);     // LDS atomic
      stage[c][p] = row;
    }
  }
  __syncthreads();
  if (tid < NCHUNK) gbase[tid] = atomicAdd(bcnt + tid, lcnt[tid]);
  __syncthreads();
  for (int c = 0; c < NCHUNK; ++c) {
    unsigned n = lcnt[c], gb = gbase[c];
    for (unsigned k = tid; k < n; k += 128)
      bucket[c * N_PTS + gb + k] = stage[c][k];
  }
}

// ---- Pass B (worklist): full F (3 MFMA), j-split 4-ways; emits F >= theta (exact) ----
__global__ __launch_bounds__(256) void k_knnBW(
    const float4* __restrict__ fragHi, const float4* __restrict__ fragLo,
    const float* __restrict__ nsq, const float* __restrict__ tau,
    const unsigned* __restrict__ bcnt, const int* __restrict__ bucket,
    unsigned* __restrict__ gcnt, unsigned long long* __restrict__ gbuf)
{
  const int c = blockIdx.x;
  const int jseg = blockIdx.y >> 8;
  const unsigned n = bcnt[c];
  const unsigned base = (unsigned)(blockIdx.y & 255) * 64;
  if (base >= n) return;

  __shared__ int   sRow[64];
  __shared__ float sTau[64];

  const int tid = threadIdx.x;
  const int w = tid >> 6, lane = tid & 63;
  const int grp = lane >> 4, col = lane & 15;
  const float INF = __int_as_float(0x7f800000);

  if (tid < 64) {
    unsigned idx = base + tid;
    int myrow = (idx < n) ? bucket[c * N_PTS + idx] : -1;
    sRow[tid] = myrow;
    sTau[tid] = (myrow >= 0) ? tau[myrow] : INF;
  }
  __syncthreads();

  const half8* fH8 = (const half8*)fragHi;
  const half8* fL8 = (const half8*)fragLo;

  half8 bh[4], bl[4];
  int   rS[4];
  float tS[4];
  #pragma unroll
  for (int s = 0; s < 4; ++s) {
    int r = sRow[s * 16 + col];
    rS[s] = r;
    tS[s] = sTau[s * 16 + col];
    int rr = r < 0 ? 0 : r;
    size_t a = (size_t)(rr >> 4) * 64 + grp * 16 + (rr & 15);
    bh[s] = fH8[a];
    bl[s] = fL8[a];
  }

  // wave w handles j-tiles jt0..jt0+1 (2 serial iterations)
  const int jt0 = c * JT_CH + jseg * (JT_CH / JSPLIT) + w * (JT_CH / (JSPLIT * 4));
  #pragma unroll
  for (int ti = 0; ti < JT_CH / (JSPLIT * 4); ++ti) {
    int jt = jt0 + ti;
    half8 ah = fH8[(size_t)jt * 64 + lane];
    half8 al = fL8[(size_t)jt * 64 + lane];
    f32x4 q = *(const f32x4*)&nsq[jt * 16 + grp * 4];
    #pragma unroll
    for (int s = 0; s < 4; ++s) {
      f32x4 acc = __builtin_amdgcn_mfma_f32_16x16x32_f16(ah, bh[s], q, 0, 0, 0);
      acc = __builtin_amdgcn_mfma_f32_16x16x32_f16(ah, bl[s], acc, 0, 0, 0);
      acc = __builtin_amdgcn_mfma_f32_16x16x32_f16(al, bh[s], acc, 0, 0, 0);
      int jbase = jt * 16 + grp * 4;
      acc.x = (jbase + 0 == rS[s]) ? -3.4e38f : acc.x;
      acc.y = (jbase + 1 == rS[s]) ? -3.4e38f : acc.y;
      acc.z = (jbase + 2 == rS[s]) ? -3.4e38f : acc.z;
      acc.w = (jbase + 3 == rS[s]) ? -3.4e38f : acc.w;
      float m = fmaxf(fmaxf(acc.x, acc.y), fmaxf(acc.z, acc.w));
      if (__ballot(m >= tS[s])) {
        float av[4] = {acc.x, acc.y, acc.z, acc.w};
        #pragma unroll
        for (int e = 0; e < 4; ++e) {
          if (av[e] >= tS[s]) {
            unsigned sl = atomicAdd(gcnt + rS[s], 1u);
            if (sl < (unsigned)NS) gbuf[(size_t)rS[s] * NS + sl] = pack_key(av[e], jbase + e);
          }
        }
      }
    }
  }
}

// -------- GAT + ELU + partial batch mean (16 nodes/block, 4 partials per batch) --------
__global__ __launch_bounds__(256) void k_gat(
    const float* __restrict__ h, const float* __restrict__ asrc, const float* __restrict__ adst,
    const unsigned long long* __restrict__ gbuf, const float* __restrict__ gb,
    float* __restrict__ mo_part)
{
  int b2 = blockIdx.x;                 // 1024 blocks: batch b = b2>>2, quarter qq = b2&3
  int b = b2 >> 2, qq = b2 & 3;
  int tid = threadIdx.x;
  __shared__ int4 sknn[16];
  if (tid < 16) {
    int row = b * 64 + qq * 16 + tid;
    unsigned long long K0 = ~0ull, K1 = ~0ull, K2 = ~0ull, K3 = ~0ull;
    const unsigned long long* src = gbuf + (size_t)row * NS;
    #pragma unroll
    for (int e = 0; e < NS; ++e) {
      unsigned long long cc = src[e];
      bool g = cc < K3, c0 = cc < K0, c1 = cc < K1, c2 = cc < K2;
      unsigned long long n1 = c0 ? K0 : (c1 ? cc : K1);
      unsigned long long n2 = c1 ? K1 : (c2 ? cc : K2);
      unsigned long long n3 = c2 ? K2 : (g ? cc : K3);
      K0 = c0 ? cc : K0; K1 = n1; K2 = n2; K3 = n3;
    }
    sknn[tid] = make_int4((int)(unsigned)K0, (int)(unsigned)K1,
                          (int)(unsigned)K2, (int)(unsigned)K3);
  }
  __syncthreads();

  int w = tid >> 6, lane = tid & 63;
  int da = lane, db = lane + 64;
  int ha = lane >> 5, hb = ha + 2;
  float acca = 0.f, accb = 0.f;

  #pragma unroll
  for (int t = 0; t < 4; ++t) {
    int nl = t * 4 + w;
    int n = b * 64 + qq * 16 + nl;
    int4 nb = sknn[nl];
    int nbs[5] = {nb.x, nb.y, nb.z, nb.w, n};
    float ad_a = adst[n * 4 + ha], ad_b = adst[n * 4 + hb];
    float ea[5], eb[5];
    #pragma unroll
    for (int k = 0; k < 5; ++k) {
      float va = ad_a + asrc[nbs[k] * 4 + ha];
      float vb = ad_b + asrc[nbs[k] * 4 + hb];
      ea[k] = va > 0.f ? va : 0.2f * va;
      eb[k] = vb > 0.f ? vb : 0.2f * vb;
    }
    float ma = ea[0], mb = eb[0];
    #pragma unroll
    for (int k = 1; k < 5; ++k) { ma = fmaxf(ma, ea[k]); mb = fmaxf(mb, eb[k]); }
    float sa = 0.f, sb = 0.f;
    #pragma unroll
    for (int k = 0; k < 5; ++k) {
      ea[k] = __expf(ea[k] - ma); sa += ea[k];
      eb[k] = __expf(eb[k] - mb); sb += eb[k];
    }
    float outa = 0.f, outb = 0.f;
    #pragma unroll
    for (int k = 0; k < 5; ++k) {
      const float* hr = h + (size_t)nbs[k] * 128;
      outa = fmaf(ea[k], hr[da], outa);
      outb = fmaf(eb[k], hr[db], outb);
    }
    outa = outa / sa + gb[da];
    outb = outb / sb + gb[db];
    acca += outa > 0.f ? outa : expm1f(outa);
    accb += outb > 0.f ? outb : expm1f(outb);
  }

  __shared__ float red[4][128];
  red[w][da] = acca; red[w][db] = accb;
  __syncthreads();
  if (tid < 128) {
    float s = (red[0][tid] + red[1][tid] + red[2][tid] + red[3][tid]) * (1.f / 64.f);
    mo_part[b2 * 128 + tid] = s;
  }
}

// ---------------- final FC 128 -> 2 (sums the 4 mean partials) ----------------
__global__ __launch_bounds__(64) void k_fc(
    const float* __restrict__ mo_part, const float* __restrict__ fw, const float* __restrict__ fb,
    float* __restrict__ out)
{
  int b = blockIdx.x, lane = threadIdx.x;
  float m0 = 0.f, m1 = 0.f;
  #pragma unroll
  for (int q = 0; q < 4; ++q) {
    m0 += mo_part[(b * 4 + q) * 128 + lane];
    m1 += mo_part[(b * 4 + q) * 128 + lane + 64];
  }
  float p0 = m0 * fw[lane * 2]     + m1 * fw[(lane + 64) * 2];
  float p1 = m0 * fw[lane * 2 + 1] + m1 * fw[(lane + 64) * 2 + 1];
  #pragma unroll
  for (int off = 32; off; off >>= 1) {
    p0 += __shfl_xor(p0, off, 64);
    p1 += __shfl_xor(p1, off, 64);
  }
  if (lane == 0) { out[b * 2] = p0 + fb[0]; out[b * 2 + 1] = p1 + fb[1]; }
}

extern "C" void kernel_launch(void* const* d_in, const int* in_sizes, int n_in,
                              void* d_out, int out_size, void* d_ws, size_t ws_size,
                              hipStream_t stream)
{
  const float* x   = (const float*)d_in[0];
  // d_in[1..4] = edge-MLP weights: dead code in the reference output, skipped.
  const float* gw  = (const float*)d_in[5];
  const float* as_ = (const float*)d_in[6];
  const float* ad_ = (const float*)d_in[7];
  const float* gb  = (const float*)d_in[8];
  const float* fw  = (const float*)d_in[9];
  const float* fb  = (const float*)d_in[10];

  char* ws = (char*)d_ws;
  float*  cvals  = (float*)(ws);                         // 2 MB
  float*  h      = (float*)(ws + 2097152);               // 8 MB
  float*  asrc   = (float*)(ws + 10485760);              // 256 KB
  float*  adst   = (float*)(ws + 10747904);              // 256 KB
  float4* fragHi = (float4*)(ws + 11010048);             // 1 MB
  float4* fragLo = (float4*)(ws + 12058624);             // 1 MB
  float*  nsq    = (float*)(ws + 13107200);              // 64 KB
  float*  tau    = (float*)(ws + 13172736);              // 64 KB
  unsigned* gcnt = (unsigned*)(ws + 13238272);           // 64 KB
  unsigned long long* gbuf = (unsigned long long*)(ws + 13303808); // 2 MB
  unsigned* bcnt = (unsigned*)(ws + 15400960);           // 256 B
  float2* pmax   = (float2*)(ws + 15401216);             // 2 KB (256 float2)
  int*    bucket = (int*)   (ws + 15403264);             // 2 MB
  float*  mo_part= (float*)(ws + 17500416);              // 512 KB
  float*  outp   = (float*)d_out;

  k_prep<<<NPB, 64, 0, stream>>>(x, fragHi, fragLo, nsq, gcnt, gbuf, bcnt, pmax);
  // fused: cy<32 = pass-A chunks, cy in [32,48) = 1024 feat blocks
  k_knnA<<<dim3(64, NCHUNK + 16), 256, 0, stream>>>(fragHi, nsq, cvals,
                                                    x, gw, as_, ad_, h, asrc, adst);
  k_tauwl<<<N_PTS / 64, 128, 0, stream>>>(cvals, tau, bcnt, bucket, pmax);
  k_knnBW<<<dim3(NCHUNK, 256 * JSPLIT), 256, 0, stream>>>(fragHi, fragLo, nsq, tau,
                                                          bcnt, bucket, gcnt, gbuf);
  k_gat<<<1024, 256, 0, stream>>>(h, asrc, adst, gbuf, gb, mo_part);
  k_fc<<<256, 64, 0, stream>>>(mo_part, fw, fb, outp);
}